// Round 1
// baseline (812.495 us; speedup 1.0000x reference)
//
#include <hip/hip_runtime.h>

#define NN 50000
#define NE 800000

// ---------------------------------------------------------------------------
// K1: x_l = nf@W_l+b_l ; x_r = nf@W_r+b_r ; ident = LN(nf@res_W+res_b)*g+beta
// 32 nodes per block, 256 threads. A staged transposed [feat][node] stride 33.
// ---------------------------------------------------------------------------
__global__ __launch_bounds__(256) void k1_node_transform(
    const float* __restrict__ nf,
    const float* __restrict__ W_l, const float* __restrict__ b_l,
    const float* __restrict__ W_r, const float* __restrict__ b_r,
    const float* __restrict__ res_W, const float* __restrict__ res_b,
    const float* __restrict__ res_g, const float* __restrict__ res_beta,
    float* __restrict__ x_l, float* __restrict__ x_r, float* __restrict__ ident)
{
    __shared__ float As[64 * 33];
    __shared__ float Ws[64 * 128];
    const int tid = threadIdx.x;
    const int node0 = blockIdx.x * 32;

    for (int i = tid; i < 32 * 64; i += 256) {
        int n = i >> 6, cfe = i & 63;
        int gn = node0 + n;
        As[cfe * 33 + n] = (gn < NN) ? nf[gn * 64 + cfe] : 0.f;
    }
    const int nc = tid & 31, ng = tid >> 5;
    const int c0 = nc * 4, n4 = ng * 4;
    const float* const Wm[3] = {W_l, W_r, res_W};
    const float* const bm[3] = {b_l, b_r, res_b};
    float* const om[2] = {x_l, x_r};

    for (int p = 0; p < 3; ++p) {
        __syncthreads();
        for (int i = tid; i < 2048; i += 256)
            *(float4*)(Ws + i * 4) = *(const float4*)(Wm[p] + i * 4);
        __syncthreads();
        float acc[4][4];
        #pragma unroll
        for (int r = 0; r < 4; ++r) {
            acc[r][0] = 0.f; acc[r][1] = 0.f; acc[r][2] = 0.f; acc[r][3] = 0.f;
        }
        for (int k = 0; k < 64; ++k) {
            float4 w = *(const float4*)(Ws + k * 128 + c0);
            #pragma unroll
            for (int r = 0; r < 4; ++r) {
                float a = As[k * 33 + n4 + r];
                acc[r][0] += a * w.x; acc[r][1] += a * w.y;
                acc[r][2] += a * w.z; acc[r][3] += a * w.w;
            }
        }
        float4 bia = *(const float4*)(bm[p] + c0);
        if (p < 2) {
            float* out = om[p];
            #pragma unroll
            for (int r = 0; r < 4; ++r) {
                int gn = node0 + n4 + r;
                if (gn < NN) {
                    float4 v = make_float4(acc[r][0] + bia.x, acc[r][1] + bia.y,
                                           acc[r][2] + bia.z, acc[r][3] + bia.w);
                    *(float4*)(out + gn * 128 + c0) = v;
                }
            }
        } else {
            float4 g  = *(const float4*)(res_g + c0);
            float4 be = *(const float4*)(res_beta + c0);
            #pragma unroll
            for (int r = 0; r < 4; ++r) {
                float v0 = acc[r][0] + bia.x, v1 = acc[r][1] + bia.y;
                float v2 = acc[r][2] + bia.z, v3 = acc[r][3] + bia.w;
                float s = v0 + v1 + v2 + v3;
                float q = v0*v0 + v1*v1 + v2*v2 + v3*v3;
                #pragma unroll
                for (int m = 16; m >= 1; m >>= 1) {
                    s += __shfl_xor(s, m, 64);
                    q += __shfl_xor(q, m, 64);
                }
                float mean = s * (1.f / 128.f);
                float var  = q * (1.f / 128.f) - mean * mean;
                float inv  = rsqrtf(var + 1e-5f);
                int gn = node0 + n4 + r;
                if (gn < NN) {
                    float4 v = make_float4((v0 - mean) * inv * g.x + be.x,
                                           (v1 - mean) * inv * g.y + be.y,
                                           (v2 - mean) * inv * g.z + be.z,
                                           (v3 - mean) * inv * g.w + be.w);
                    *(float4*)(ident + gn * 128 + c0) = v;
                }
            }
        }
    }
}

// ---------------------------------------------------------------------------
// K2: per-edge logits + degree count. One wave per edge, grid-strided so W_e
// columns stay in registers (32 VGPRs) for the whole kernel.
// ---------------------------------------------------------------------------
__global__ __launch_bounds__(256) void k2_edge_logits(
    const float* __restrict__ ef, const int* __restrict__ eidx,
    const float* __restrict__ W_e, const float* __restrict__ att,
    const float* __restrict__ x_l, const float* __restrict__ x_r,
    float* __restrict__ logits, int* __restrict__ deg)
{
    const int lane = threadIdx.x & 63;
    const int wave = (blockIdx.x * 256 + threadIdx.x) >> 6;
    const int nwaves = gridDim.x * 4;
    const int c = lane * 2;

    float wex[16], wey[16];
    #pragma unroll
    for (int k = 0; k < 16; ++k) {
        float2 w = *(const float2*)(W_e + k * 128 + c);
        wex[k] = w.x; wey[k] = w.y;
    }
    const float2 a2 = *(const float2*)(att + c);

    for (int e = wave; e < NE; e += nwaves) {
        int src = eidx[e];
        int dst = eidx[NE + e];
        const float4* efp = (const float4*)(ef + e * 16);
        float4 f0 = efp[0], f1 = efp[1], f2 = efp[2], f3 = efp[3];
        float fv[16] = {f0.x, f0.y, f0.z, f0.w, f1.x, f1.y, f1.z, f1.w,
                        f2.x, f2.y, f2.z, f2.w, f3.x, f3.y, f3.z, f3.w};
        float evx = 0.f, evy = 0.f;
        #pragma unroll
        for (int k = 0; k < 16; ++k) { evx += fv[k] * wex[k]; evy += fv[k] * wey[k]; }
        float2 xl = *(const float2*)(x_l + src * 128 + c);
        float2 xr = *(const float2*)(x_r + dst * 128 + c);
        float mx = xl.x + xr.x + evx;
        float my = xl.y + xr.y + evy;
        float lx = mx >= 0.f ? mx : 0.2f * mx;
        float ly = my >= 0.f ? my : 0.2f * my;
        float p = lx * a2.x + ly * a2.y;
        p += __shfl_xor(p, 8, 64);
        p += __shfl_xor(p, 4, 64);
        p += __shfl_xor(p, 2, 64);
        p += __shfl_xor(p, 1, 64);
        if ((lane & 15) == 0) logits[e * 4 + (lane >> 4)] = p;
        if (lane == 0) atomicAdd(deg + dst, 1);
    }
}

// ---------------------------------------------------------------------------
// K3: single-block exclusive scan of deg -> row_start (N+1) and cursor copy.
// ---------------------------------------------------------------------------
__global__ __launch_bounds__(256) void k3_scan(
    const int* __restrict__ deg, int* __restrict__ row_start, int* __restrict__ cursor)
{
    __shared__ int wsum[4];
    __shared__ int carry_s;
    const int tid = threadIdx.x;
    const int lane = tid & 63;
    const int wid = tid >> 6;
    if (tid == 0) carry_s = 0;
    __syncthreads();
    for (int base = 0; base < NN; base += 1024) {
        int i0 = base + tid * 4;
        int4 v = make_int4(0, 0, 0, 0);
        if (i0 + 3 < NN) {
            v = *(const int4*)(deg + i0);
        } else {
            if (i0 + 0 < NN) v.x = deg[i0 + 0];
            if (i0 + 1 < NN) v.y = deg[i0 + 1];
            if (i0 + 2 < NN) v.z = deg[i0 + 2];
            if (i0 + 3 < NN) v.w = deg[i0 + 3];
        }
        int tsum = v.x + v.y + v.z + v.w;
        int sc = tsum;
        #pragma unroll
        for (int m = 1; m < 64; m <<= 1) {
            int t = __shfl_up(sc, m, 64);
            if (lane >= m) sc += t;
        }
        if (lane == 63) wsum[wid] = sc;
        __syncthreads();
        int woff = carry_s;
        for (int w = 0; w < wid; ++w) woff += wsum[w];
        int e0 = woff + sc - tsum;
        int e1 = e0 + v.x, e2 = e1 + v.y, e3 = e2 + v.z;
        if (i0 + 0 < NN) { row_start[i0 + 0] = e0; cursor[i0 + 0] = e0; }
        if (i0 + 1 < NN) { row_start[i0 + 1] = e1; cursor[i0 + 1] = e1; }
        if (i0 + 2 < NN) { row_start[i0 + 2] = e2; cursor[i0 + 2] = e2; }
        if (i0 + 3 < NN) { row_start[i0 + 3] = e3; cursor[i0 + 3] = e3; }
        __syncthreads();
        if (tid == 0) carry_s += wsum[0] + wsum[1] + wsum[2] + wsum[3];
        __syncthreads();
    }
    if (threadIdx.x == 0) row_start[NN] = carry_s;
}

// ---------------------------------------------------------------------------
// K4: scatter edge ids into dst-sorted CSR order.
// ---------------------------------------------------------------------------
__global__ __launch_bounds__(256) void k4_scatter(
    const int* __restrict__ eidx, int* __restrict__ cursor, int* __restrict__ csr)
{
    int e = blockIdx.x * 256 + threadIdx.x;
    if (e >= NE) return;
    int dst = eidx[NE + e];
    int pos = atomicAdd(cursor + dst, 1);
    csr[pos] = e;
}

// ---------------------------------------------------------------------------
// K5: per-node softmax denominator + weighted aggregation. One wave per node.
// ---------------------------------------------------------------------------
__global__ __launch_bounds__(256) void k5_aggregate(
    const int* __restrict__ csr, const int* __restrict__ row_start,
    const int* __restrict__ eidx, const float* __restrict__ logits,
    const float* __restrict__ x_l, const float* __restrict__ gat_bias,
    float* __restrict__ gat_out)
{
    const int lane = threadIdx.x & 63;
    const int node = (blockIdx.x * 256 + threadIdx.x) >> 6;
    if (node >= NN) return;
    const int s  = row_start[node];
    const int ep = row_start[node + 1];

    float d0 = 0.f, d1 = 0.f, d2 = 0.f, d3 = 0.f;
    for (int j = s + lane; j < ep; j += 64) {
        int eid = csr[j];
        float4 lg = *(const float4*)(logits + eid * 4);
        d0 += __expf(lg.x); d1 += __expf(lg.y); d2 += __expf(lg.z); d3 += __expf(lg.w);
    }
    #pragma unroll
    for (int m = 32; m >= 1; m >>= 1) {
        d0 += __shfl_xor(d0, m, 64);
        d1 += __shfl_xor(d1, m, 64);
        d2 += __shfl_xor(d2, m, 64);
        d3 += __shfl_xor(d3, m, 64);
    }
    const int h = lane >> 4;
    float den = (h == 0) ? d0 : (h == 1) ? d1 : (h == 2) ? d2 : d3;
    float rden = 1.f / den;
    const int c = lane * 2;
    float a0 = 0.f, a1 = 0.f;
    for (int j = s; j < ep; ++j) {
        int eid = csr[j];
        int srcn = eidx[eid];
        float lg = logits[eid * 4 + h];
        float w = __expf(lg) * rden;
        float2 xl = *(const float2*)(x_l + srcn * 128 + c);
        a0 += w * xl.x;
        a1 += w * xl.y;
    }
    float2 gb = *(const float2*)(gat_bias + c);
    float2 o; o.x = a0 + gb.x; o.y = a1 + gb.y;
    *(float2*)(gat_out + node * 128 + c) = o;
}

// ---------------------------------------------------------------------------
// K6: h = relu(LN(concat(nf,gat)@W0+b0)); h = relu(LN(h@W1+b1)); out = ident+h
// 32 nodes per block, k-tiled (BK=32) LDS GEMMs.
// ---------------------------------------------------------------------------
__global__ __launch_bounds__(256) void k6_mlp(
    const float* __restrict__ nf, const float* __restrict__ gat,
    const float* __restrict__ ident,
    const float* __restrict__ W0, const float* __restrict__ b0,
    const float* __restrict__ g0, const float* __restrict__ be0,
    const float* __restrict__ W1, const float* __restrict__ b1,
    const float* __restrict__ g1, const float* __restrict__ be1,
    float* __restrict__ out)
{
    __shared__ float As[192 * 33];
    __shared__ float Ws[32 * 128];
    __shared__ float Hs[128 * 33];
    const int tid = threadIdx.x;
    const int node0 = blockIdx.x * 32;

    for (int i = tid; i < 32 * 192; i += 256) {
        int n = i / 192, cc = i % 192;
        int gn = node0 + n;
        float v = 0.f;
        if (gn < NN) v = (cc < 64) ? nf[gn * 64 + cc] : gat[gn * 128 + (cc - 64)];
        As[cc * 33 + n] = v;
    }
    const int nc = tid & 31, ng = tid >> 5;
    const int c0 = nc * 4, n4 = ng * 4;

    float acc[4][4];
    #pragma unroll
    for (int r = 0; r < 4; ++r) {
        acc[r][0] = 0.f; acc[r][1] = 0.f; acc[r][2] = 0.f; acc[r][3] = 0.f;
    }
    __syncthreads();

    for (int kb = 0; kb < 6; ++kb) {
        for (int i = tid; i < 1024; i += 256)
            *(float4*)(Ws + i * 4) = *(const float4*)(W0 + kb * 4096 + i * 4);
        __syncthreads();
        for (int k = 0; k < 32; ++k) {
            float4 w = *(const float4*)(Ws + k * 128 + c0);
            int krow = (kb * 32 + k) * 33;
            #pragma unroll
            for (int r = 0; r < 4; ++r) {
                float a = As[krow + n4 + r];
                acc[r][0] += a * w.x; acc[r][1] += a * w.y;
                acc[r][2] += a * w.z; acc[r][3] += a * w.w;
            }
        }
        __syncthreads();
    }

    {
        float4 bb = *(const float4*)(b0 + c0);
        float4 gg = *(const float4*)(g0 + c0);
        float4 bt = *(const float4*)(be0 + c0);
        #pragma unroll
        for (int r = 0; r < 4; ++r) {
            float v0 = acc[r][0] + bb.x, v1 = acc[r][1] + bb.y;
            float v2 = acc[r][2] + bb.z, v3 = acc[r][3] + bb.w;
            float s = v0 + v1 + v2 + v3;
            float q = v0*v0 + v1*v1 + v2*v2 + v3*v3;
            #pragma unroll
            for (int m = 16; m >= 1; m >>= 1) {
                s += __shfl_xor(s, m, 64);
                q += __shfl_xor(q, m, 64);
            }
            float mean = s * (1.f / 128.f);
            float inv  = rsqrtf(q * (1.f / 128.f) - mean * mean + 1e-5f);
            int n = n4 + r;
            Hs[(c0 + 0) * 33 + n] = fmaxf((v0 - mean) * inv * gg.x + bt.x, 0.f);
            Hs[(c0 + 1) * 33 + n] = fmaxf((v1 - mean) * inv * gg.y + bt.y, 0.f);
            Hs[(c0 + 2) * 33 + n] = fmaxf((v2 - mean) * inv * gg.z + bt.z, 0.f);
            Hs[(c0 + 3) * 33 + n] = fmaxf((v3 - mean) * inv * gg.w + bt.w, 0.f);
            acc[r][0] = 0.f; acc[r][1] = 0.f; acc[r][2] = 0.f; acc[r][3] = 0.f;
        }
    }
    __syncthreads();

    for (int kb = 0; kb < 4; ++kb) {
        for (int i = tid; i < 1024; i += 256)
            *(float4*)(Ws + i * 4) = *(const float4*)(W1 + kb * 4096 + i * 4);
        __syncthreads();
        for (int k = 0; k < 32; ++k) {
            float4 w = *(const float4*)(Ws + k * 128 + c0);
            int krow = (kb * 32 + k) * 33;
            #pragma unroll
            for (int r = 0; r < 4; ++r) {
                float a = Hs[krow + n4 + r];
                acc[r][0] += a * w.x; acc[r][1] += a * w.y;
                acc[r][2] += a * w.z; acc[r][3] += a * w.w;
            }
        }
        __syncthreads();
    }

    {
        float4 bb = *(const float4*)(b1 + c0);
        float4 gg = *(const float4*)(g1 + c0);
        float4 bt = *(const float4*)(be1 + c0);
        #pragma unroll
        for (int r = 0; r < 4; ++r) {
            float v0 = acc[r][0] + bb.x, v1 = acc[r][1] + bb.y;
            float v2 = acc[r][2] + bb.z, v3 = acc[r][3] + bb.w;
            float s = v0 + v1 + v2 + v3;
            float q = v0*v0 + v1*v1 + v2*v2 + v3*v3;
            #pragma unroll
            for (int m = 16; m >= 1; m >>= 1) {
                s += __shfl_xor(s, m, 64);
                q += __shfl_xor(q, m, 64);
            }
            float mean = s * (1.f / 128.f);
            float inv  = rsqrtf(q * (1.f / 128.f) - mean * mean + 1e-5f);
            float h0 = fmaxf((v0 - mean) * inv * gg.x + bt.x, 0.f);
            float h1 = fmaxf((v1 - mean) * inv * gg.y + bt.y, 0.f);
            float h2 = fmaxf((v2 - mean) * inv * gg.z + bt.z, 0.f);
            float h3 = fmaxf((v3 - mean) * inv * gg.w + bt.w, 0.f);
            int gn = node0 + n4 + r;
            if (gn < NN) {
                float4 idv = *(const float4*)(ident + gn * 128 + c0);
                float4 v = make_float4(idv.x + h0, idv.y + h1, idv.z + h2, idv.w + h3);
                *(float4*)(out + gn * 128 + c0) = v;
            }
        }
    }
}

// ---------------------------------------------------------------------------
extern "C" void kernel_launch(void* const* d_in, const int* in_sizes, int n_in,
                              void* d_out, int out_size, void* d_ws, size_t ws_size,
                              hipStream_t stream)
{
    const float* nf       = (const float*)d_in[0];
    const float* ef       = (const float*)d_in[1];
    const int*   eidx     = (const int*)d_in[2];
    const float* W_l      = (const float*)d_in[3];
    const float* b_l      = (const float*)d_in[4];
    const float* W_r      = (const float*)d_in[5];
    const float* b_r      = (const float*)d_in[6];
    const float* W_e      = (const float*)d_in[7];
    const float* att      = (const float*)d_in[8];
    const float* gat_bias = (const float*)d_in[9];
    const float* res_W    = (const float*)d_in[10];
    const float* res_b    = (const float*)d_in[11];
    const float* res_g    = (const float*)d_in[12];
    const float* res_beta = (const float*)d_in[13];
    const float* W0       = (const float*)d_in[14];
    const float* b0       = (const float*)d_in[15];
    const float* g0       = (const float*)d_in[16];
    const float* beta0    = (const float*)d_in[17];
    const float* W1       = (const float*)d_in[18];
    const float* b1       = (const float*)d_in[19];
    const float* g1       = (const float*)d_in[20];
    const float* beta1    = (const float*)d_in[21];
    float* out = (float*)d_out;

    char* ws = (char*)d_ws;
    size_t off = 0;
    auto alloc = [&](size_t bytes) -> void* {
        void* p = ws + off;
        off += (bytes + 255) & ~(size_t)255;
        return p;
    };
    float* x_l     = (float*)alloc((size_t)NN * 128 * 4);
    float* x_r     = (float*)alloc((size_t)NN * 128 * 4);
    float* ident   = (float*)alloc((size_t)NN * 128 * 4);
    float* logits  = (float*)alloc((size_t)NE * 4 * 4);
    int* deg       = (int*)alloc((size_t)NN * 4);
    int* row_start = (int*)alloc((size_t)(NN + 1) * 4);
    int* cursor    = (int*)alloc((size_t)NN * 4);
    int* csr       = (int*)alloc((size_t)NE * 4);
    float* gat_out = x_r;  // x_r is dead after K2; reuse its buffer

    hipMemsetAsync(deg, 0, (size_t)NN * 4, stream);

    k1_node_transform<<<(NN + 31) / 32, 256, 0, stream>>>(
        nf, W_l, b_l, W_r, b_r, res_W, res_b, res_g, res_beta, x_l, x_r, ident);

    k2_edge_logits<<<4096, 256, 0, stream>>>(
        ef, eidx, W_e, att, x_l, x_r, logits, deg);

    k3_scan<<<1, 256, 0, stream>>>(deg, row_start, cursor);

    k4_scatter<<<(NE + 255) / 256, 256, 0, stream>>>(eidx, cursor, csr);

    k5_aggregate<<<(NN * 64 + 255) / 256, 256, 0, stream>>>(
        csr, row_start, eidx, logits, x_l, gat_bias, gat_out);

    k6_mlp<<<(NN + 31) / 32, 256, 0, stream>>>(
        nf, gat_out, ident, W0, b0, g0, beta0, W1, b1, g1, beta1, out);
}

// Round 2
// 750.741 us; speedup vs baseline: 1.0823x; 1.0823x over previous
//
#include <hip/hip_runtime.h>

#define NN 50000
#define NE 800000

// ---------------------------------------------------------------------------
// K1: x_l = nf@W_l+b_l ; x_r = nf@W_r+b_r ; ident = LN(nf@res_W+res_b)*g+beta
// 32 nodes per block, 256 threads. A staged transposed [feat][node] stride 33.
// ---------------------------------------------------------------------------
__global__ __launch_bounds__(256) void k1_node_transform(
    const float* __restrict__ nf,
    const float* __restrict__ W_l, const float* __restrict__ b_l,
    const float* __restrict__ W_r, const float* __restrict__ b_r,
    const float* __restrict__ res_W, const float* __restrict__ res_b,
    const float* __restrict__ res_g, const float* __restrict__ res_beta,
    float* __restrict__ x_l, float* __restrict__ x_r, float* __restrict__ ident)
{
    __shared__ float As[64 * 33];
    __shared__ float Ws[64 * 128];
    const int tid = threadIdx.x;
    const int node0 = blockIdx.x * 32;

    for (int i = tid; i < 32 * 64; i += 256) {
        int n = i >> 6, cfe = i & 63;
        int gn = node0 + n;
        As[cfe * 33 + n] = (gn < NN) ? nf[gn * 64 + cfe] : 0.f;
    }
    const int nc = tid & 31, ng = tid >> 5;
    const int c0 = nc * 4, n4 = ng * 4;
    const float* const Wm[3] = {W_l, W_r, res_W};
    const float* const bm[3] = {b_l, b_r, res_b};
    float* const om[2] = {x_l, x_r};

    for (int p = 0; p < 3; ++p) {
        __syncthreads();
        for (int i = tid; i < 2048; i += 256)
            *(float4*)(Ws + i * 4) = *(const float4*)(Wm[p] + i * 4);
        __syncthreads();
        float acc[4][4];
        #pragma unroll
        for (int r = 0; r < 4; ++r) {
            acc[r][0] = 0.f; acc[r][1] = 0.f; acc[r][2] = 0.f; acc[r][3] = 0.f;
        }
        for (int k = 0; k < 64; ++k) {
            float4 w = *(const float4*)(Ws + k * 128 + c0);
            #pragma unroll
            for (int r = 0; r < 4; ++r) {
                float a = As[k * 33 + n4 + r];
                acc[r][0] += a * w.x; acc[r][1] += a * w.y;
                acc[r][2] += a * w.z; acc[r][3] += a * w.w;
            }
        }
        float4 bia = *(const float4*)(bm[p] + c0);
        if (p < 2) {
            float* out = om[p];
            #pragma unroll
            for (int r = 0; r < 4; ++r) {
                int gn = node0 + n4 + r;
                if (gn < NN) {
                    float4 v = make_float4(acc[r][0] + bia.x, acc[r][1] + bia.y,
                                           acc[r][2] + bia.z, acc[r][3] + bia.w);
                    *(float4*)(out + gn * 128 + c0) = v;
                }
            }
        } else {
            float4 g  = *(const float4*)(res_g + c0);
            float4 be = *(const float4*)(res_beta + c0);
            #pragma unroll
            for (int r = 0; r < 4; ++r) {
                float v0 = acc[r][0] + bia.x, v1 = acc[r][1] + bia.y;
                float v2 = acc[r][2] + bia.z, v3 = acc[r][3] + bia.w;
                float s = v0 + v1 + v2 + v3;
                float q = v0*v0 + v1*v1 + v2*v2 + v3*v3;
                #pragma unroll
                for (int m = 16; m >= 1; m >>= 1) {
                    s += __shfl_xor(s, m, 64);
                    q += __shfl_xor(q, m, 64);
                }
                float mean = s * (1.f / 128.f);
                float var  = q * (1.f / 128.f) - mean * mean;
                float inv  = rsqrtf(var + 1e-5f);
                int gn = node0 + n4 + r;
                if (gn < NN) {
                    float4 v = make_float4((v0 - mean) * inv * g.x + be.x,
                                           (v1 - mean) * inv * g.y + be.y,
                                           (v2 - mean) * inv * g.z + be.z,
                                           (v3 - mean) * inv * g.w + be.w);
                    *(float4*)(ident + gn * 128 + c0) = v;
                }
            }
        }
    }
}

// ---------------------------------------------------------------------------
// K2a: degree count only.
// ---------------------------------------------------------------------------
__global__ __launch_bounds__(256) void k2a_degree(
    const int* __restrict__ eidx, int* __restrict__ deg)
{
    int e = blockIdx.x * 256 + threadIdx.x;
    if (e >= NE) return;
    atomicAdd(deg + eidx[NE + e], 1);
}

// ---------------------------------------------------------------------------
// K3: single-block exclusive scan of deg -> row_start (N+1) and cursor copy.
// ---------------------------------------------------------------------------
__global__ __launch_bounds__(256) void k3_scan(
    const int* __restrict__ deg, int* __restrict__ row_start, int* __restrict__ cursor)
{
    __shared__ int wsum[4];
    __shared__ int carry_s;
    const int tid = threadIdx.x;
    const int lane = tid & 63;
    const int wid = tid >> 6;
    if (tid == 0) carry_s = 0;
    __syncthreads();
    for (int base = 0; base < NN; base += 1024) {
        int i0 = base + tid * 4;
        int4 v = make_int4(0, 0, 0, 0);
        if (i0 + 3 < NN) {
            v = *(const int4*)(deg + i0);
        } else {
            if (i0 + 0 < NN) v.x = deg[i0 + 0];
            if (i0 + 1 < NN) v.y = deg[i0 + 1];
            if (i0 + 2 < NN) v.z = deg[i0 + 2];
            if (i0 + 3 < NN) v.w = deg[i0 + 3];
        }
        int tsum = v.x + v.y + v.z + v.w;
        int sc = tsum;
        #pragma unroll
        for (int m = 1; m < 64; m <<= 1) {
            int t = __shfl_up(sc, m, 64);
            if (lane >= m) sc += t;
        }
        if (lane == 63) wsum[wid] = sc;
        __syncthreads();
        int woff = carry_s;
        for (int w = 0; w < wid; ++w) woff += wsum[w];
        int e0 = woff + sc - tsum;
        int e1 = e0 + v.x, e2 = e1 + v.y, e3 = e2 + v.z;
        if (i0 + 0 < NN) { row_start[i0 + 0] = e0; cursor[i0 + 0] = e0; }
        if (i0 + 1 < NN) { row_start[i0 + 1] = e1; cursor[i0 + 1] = e1; }
        if (i0 + 2 < NN) { row_start[i0 + 2] = e2; cursor[i0 + 2] = e2; }
        if (i0 + 3 < NN) { row_start[i0 + 3] = e3; cursor[i0 + 3] = e3; }
        __syncthreads();
        if (tid == 0) carry_s += wsum[0] + wsum[1] + wsum[2] + wsum[3];
        __syncthreads();
    }
    if (threadIdx.x == 0) row_start[NN] = carry_s;
}

// ---------------------------------------------------------------------------
// K4: scatter edge ids AND src node ids into dst-sorted CSR order.
// Storing src here removes one dependent random load from K5's inner loop.
// ---------------------------------------------------------------------------
__global__ __launch_bounds__(256) void k4_scatter(
    const int* __restrict__ eidx, int* __restrict__ cursor,
    int* __restrict__ csr_eid, int* __restrict__ csr_src)
{
    int e = blockIdx.x * 256 + threadIdx.x;
    if (e >= NE) return;
    int dst = eidx[NE + e];
    int srcn = eidx[e];
    int pos = atomicAdd(cursor + dst, 1);
    csr_eid[pos] = e;
    csr_src[pos] = srcn;
}

// ---------------------------------------------------------------------------
// K5: fused GATv2 attention + aggregation. One wave per node.
// Single-pass unnormalized softmax: num += exp(l)*x_l[src], den += exp(l).
// Logits are ~N(0,0.2) (weights scaled by 0.05), exp cannot overflow, so no
// max-subtraction is needed (softmax is shift-invariant).
// W_e columns (2 per lane => 32 VGPRs) and x_r[node] stay in registers;
// __launch_bounds__(256,4) caps at 128 VGPRs so the compiler keeps them.
// ---------------------------------------------------------------------------
__global__ __launch_bounds__(256, 4) void k5_attn_aggregate(
    const int* __restrict__ csr_eid, const int* __restrict__ csr_src,
    const int* __restrict__ row_start,
    const float* __restrict__ ef, const float* __restrict__ W_e,
    const float* __restrict__ att,
    const float* __restrict__ x_l, const float* __restrict__ x_r,
    const float* __restrict__ gat_bias,
    float* __restrict__ gat_out)
{
    const int lane = threadIdx.x & 63;
    const int node = (blockIdx.x * 256 + threadIdx.x) >> 6;
    if (node >= NN) return;
    const int c = lane * 2;

    // per-lane W_e columns and attention weights (resident for whole kernel)
    float wex[16], wey[16];
    #pragma unroll
    for (int k = 0; k < 16; ++k) {
        float2 w = *(const float2*)(W_e + k * 128 + c);
        wex[k] = w.x; wey[k] = w.y;
    }
    const float2 a2 = *(const float2*)(att + c);
    const float2 xr = *(const float2*)(x_r + node * 128 + c);

    const int s  = row_start[node];
    const int ep = row_start[node + 1];

    float den = 0.f, n0 = 0.f, n1 = 0.f;
    for (int j = s; j < ep; ++j) {
        int eid  = csr_eid[j];
        int srcn = csr_src[j];
        const float4* efp = (const float4*)(ef + eid * 16);
        float2 xl = *(const float2*)(x_l + srcn * 128 + c);
        float4 f0 = efp[0], f1 = efp[1], f2 = efp[2], f3 = efp[3];
        float fv[16] = {f0.x, f0.y, f0.z, f0.w, f1.x, f1.y, f1.z, f1.w,
                        f2.x, f2.y, f2.z, f2.w, f3.x, f3.y, f3.z, f3.w};
        float evx = 0.f, evy = 0.f;
        #pragma unroll
        for (int k = 0; k < 16; ++k) { evx += fv[k] * wex[k]; evy += fv[k] * wey[k]; }
        float mx = xl.x + xr.x + evx;
        float my = xl.y + xr.y + evy;
        float lx = mx >= 0.f ? mx : 0.2f * mx;
        float ly = my >= 0.f ? my : 0.2f * my;
        float p = lx * a2.x + ly * a2.y;
        // sum across the 16 lanes of this head
        p += __shfl_xor(p, 8, 64);
        p += __shfl_xor(p, 4, 64);
        p += __shfl_xor(p, 2, 64);
        p += __shfl_xor(p, 1, 64);
        float ev = __expf(p);
        den += ev;
        n0 += ev * xl.x;
        n1 += ev * xl.y;
    }
    float rden = (den > 0.f) ? (1.f / den) : 0.f;
    float2 gb = *(const float2*)(gat_bias + c);
    float2 o; o.x = n0 * rden + gb.x; o.y = n1 * rden + gb.y;
    *(float2*)(gat_out + node * 128 + c) = o;
}

// ---------------------------------------------------------------------------
// K6: h = relu(LN(concat(nf,gat)@W0+b0)); h = relu(LN(h@W1+b1)); out = ident+h
// 32 nodes per block, k-tiled (BK=32) LDS GEMMs.
// ---------------------------------------------------------------------------
__global__ __launch_bounds__(256) void k6_mlp(
    const float* __restrict__ nf, const float* __restrict__ gat,
    const float* __restrict__ ident,
    const float* __restrict__ W0, const float* __restrict__ b0,
    const float* __restrict__ g0, const float* __restrict__ be0,
    const float* __restrict__ W1, const float* __restrict__ b1,
    const float* __restrict__ g1, const float* __restrict__ be1,
    float* __restrict__ out)
{
    __shared__ float As[192 * 33];
    __shared__ float Ws[32 * 128];
    __shared__ float Hs[128 * 33];
    const int tid = threadIdx.x;
    const int node0 = blockIdx.x * 32;

    for (int i = tid; i < 32 * 192; i += 256) {
        int n = i / 192, cc = i % 192;
        int gn = node0 + n;
        float v = 0.f;
        if (gn < NN) v = (cc < 64) ? nf[gn * 64 + cc] : gat[gn * 128 + (cc - 64)];
        As[cc * 33 + n] = v;
    }
    const int nc = tid & 31, ng = tid >> 5;
    const int c0 = nc * 4, n4 = ng * 4;

    float acc[4][4];
    #pragma unroll
    for (int r = 0; r < 4; ++r) {
        acc[r][0] = 0.f; acc[r][1] = 0.f; acc[r][2] = 0.f; acc[r][3] = 0.f;
    }
    __syncthreads();

    for (int kb = 0; kb < 6; ++kb) {
        for (int i = tid; i < 1024; i += 256)
            *(float4*)(Ws + i * 4) = *(const float4*)(W0 + kb * 4096 + i * 4);
        __syncthreads();
        for (int k = 0; k < 32; ++k) {
            float4 w = *(const float4*)(Ws + k * 128 + c0);
            int krow = (kb * 32 + k) * 33;
            #pragma unroll
            for (int r = 0; r < 4; ++r) {
                float a = As[krow + n4 + r];
                acc[r][0] += a * w.x; acc[r][1] += a * w.y;
                acc[r][2] += a * w.z; acc[r][3] += a * w.w;
            }
        }
        __syncthreads();
    }

    {
        float4 bb = *(const float4*)(b0 + c0);
        float4 gg = *(const float4*)(g0 + c0);
        float4 bt = *(const float4*)(be0 + c0);
        #pragma unroll
        for (int r = 0; r < 4; ++r) {
            float v0 = acc[r][0] + bb.x, v1 = acc[r][1] + bb.y;
            float v2 = acc[r][2] + bb.z, v3 = acc[r][3] + bb.w;
            float s = v0 + v1 + v2 + v3;
            float q = v0*v0 + v1*v1 + v2*v2 + v3*v3;
            #pragma unroll
            for (int m = 16; m >= 1; m >>= 1) {
                s += __shfl_xor(s, m, 64);
                q += __shfl_xor(q, m, 64);
            }
            float mean = s * (1.f / 128.f);
            float inv  = rsqrtf(q * (1.f / 128.f) - mean * mean + 1e-5f);
            int n = n4 + r;
            Hs[(c0 + 0) * 33 + n] = fmaxf((v0 - mean) * inv * gg.x + bt.x, 0.f);
            Hs[(c0 + 1) * 33 + n] = fmaxf((v1 - mean) * inv * gg.y + bt.y, 0.f);
            Hs[(c0 + 2) * 33 + n] = fmaxf((v2 - mean) * inv * gg.z + bt.z, 0.f);
            Hs[(c0 + 3) * 33 + n] = fmaxf((v3 - mean) * inv * gg.w + bt.w, 0.f);
            acc[r][0] = 0.f; acc[r][1] = 0.f; acc[r][2] = 0.f; acc[r][3] = 0.f;
        }
    }
    __syncthreads();

    for (int kb = 0; kb < 4; ++kb) {
        for (int i = tid; i < 1024; i += 256)
            *(float4*)(Ws + i * 4) = *(const float4*)(W1 + kb * 4096 + i * 4);
        __syncthreads();
        for (int k = 0; k < 32; ++k) {
            float4 w = *(const float4*)(Ws + k * 128 + c0);
            int krow = (kb * 32 + k) * 33;
            #pragma unroll
            for (int r = 0; r < 4; ++r) {
                float a = Hs[krow + n4 + r];
                acc[r][0] += a * w.x; acc[r][1] += a * w.y;
                acc[r][2] += a * w.z; acc[r][3] += a * w.w;
            }
        }
        __syncthreads();
    }

    {
        float4 bb = *(const float4*)(b1 + c0);
        float4 gg = *(const float4*)(g1 + c0);
        float4 bt = *(const float4*)(be1 + c0);
        #pragma unroll
        for (int r = 0; r < 4; ++r) {
            float v0 = acc[r][0] + bb.x, v1 = acc[r][1] + bb.y;
            float v2 = acc[r][2] + bb.z, v3 = acc[r][3] + bb.w;
            float s = v0 + v1 + v2 + v3;
            float q = v0*v0 + v1*v1 + v2*v2 + v3*v3;
            #pragma unroll
            for (int m = 16; m >= 1; m >>= 1) {
                s += __shfl_xor(s, m, 64);
                q += __shfl_xor(q, m, 64);
            }
            float mean = s * (1.f / 128.f);
            float inv  = rsqrtf(q * (1.f / 128.f) - mean * mean + 1e-5f);
            float h0 = fmaxf((v0 - mean) * inv * gg.x + bt.x, 0.f);
            float h1 = fmaxf((v1 - mean) * inv * gg.y + bt.y, 0.f);
            float h2 = fmaxf((v2 - mean) * inv * gg.z + bt.z, 0.f);
            float h3 = fmaxf((v3 - mean) * inv * gg.w + bt.w, 0.f);
            int gn = node0 + n4 + r;
            if (gn < NN) {
                float4 idv = *(const float4*)(ident + gn * 128 + c0);
                float4 v = make_float4(idv.x + h0, idv.y + h1, idv.z + h2, idv.w + h3);
                *(float4*)(out + gn * 128 + c0) = v;
            }
        }
    }
}

// ---------------------------------------------------------------------------
extern "C" void kernel_launch(void* const* d_in, const int* in_sizes, int n_in,
                              void* d_out, int out_size, void* d_ws, size_t ws_size,
                              hipStream_t stream)
{
    const float* nf       = (const float*)d_in[0];
    const float* ef       = (const float*)d_in[1];
    const int*   eidx     = (const int*)d_in[2];
    const float* W_l      = (const float*)d_in[3];
    const float* b_l      = (const float*)d_in[4];
    const float* W_r      = (const float*)d_in[5];
    const float* b_r      = (const float*)d_in[6];
    const float* W_e      = (const float*)d_in[7];
    const float* att      = (const float*)d_in[8];
    const float* gat_bias = (const float*)d_in[9];
    const float* res_W    = (const float*)d_in[10];
    const float* res_b    = (const float*)d_in[11];
    const float* res_g    = (const float*)d_in[12];
    const float* res_beta = (const float*)d_in[13];
    const float* W0       = (const float*)d_in[14];
    const float* b0       = (const float*)d_in[15];
    const float* g0       = (const float*)d_in[16];
    const float* beta0    = (const float*)d_in[17];
    const float* W1       = (const float*)d_in[18];
    const float* b1       = (const float*)d_in[19];
    const float* g1       = (const float*)d_in[20];
    const float* beta1    = (const float*)d_in[21];
    float* out = (float*)d_out;

    char* ws = (char*)d_ws;
    size_t off = 0;
    auto alloc = [&](size_t bytes) -> void* {
        void* p = ws + off;
        off += (bytes + 255) & ~(size_t)255;
        return p;
    };
    float* x_l     = (float*)alloc((size_t)NN * 128 * 4);
    float* x_r     = (float*)alloc((size_t)NN * 128 * 4);
    float* ident   = (float*)alloc((size_t)NN * 128 * 4);
    int* deg       = (int*)alloc((size_t)NN * 4);
    int* row_start = (int*)alloc((size_t)(NN + 1) * 4);
    int* cursor    = (int*)alloc((size_t)NN * 4);
    int* csr_eid   = (int*)alloc((size_t)NE * 4);
    int* csr_src   = (int*)alloc((size_t)NE * 4);
    float* gat_out = x_l;  // x_l is dead after K5 reads it; safe? NO - K5 reads
                           // x_l while writing gat_out. Use a separate buffer.
    gat_out        = (float*)alloc((size_t)NN * 128 * 4);

    hipMemsetAsync(deg, 0, (size_t)NN * 4, stream);

    k1_node_transform<<<(NN + 31) / 32, 256, 0, stream>>>(
        nf, W_l, b_l, W_r, b_r, res_W, res_b, res_g, res_beta, x_l, x_r, ident);

    k2a_degree<<<(NE + 255) / 256, 256, 0, stream>>>(eidx, deg);

    k3_scan<<<1, 256, 0, stream>>>(deg, row_start, cursor);

    k4_scatter<<<(NE + 255) / 256, 256, 0, stream>>>(eidx, cursor, csr_eid, csr_src);

    k5_attn_aggregate<<<(NN * 64 + 255) / 256, 256, 0, stream>>>(
        csr_eid, csr_src, row_start, ef, W_e, att, x_l, x_r, gat_bias, gat_out);

    k6_mlp<<<(NN + 31) / 32, 256, 0, stream>>>(
        nf, gat_out, ident, W0, b0, g0, beta0, W1, b1, g1, beta1, out);
}

// Round 3
// 655.902 us; speedup vs baseline: 1.2387x; 1.1446x over previous
//
#include <hip/hip_runtime.h>

#define NN 50000
#define NE 800000

// ---------------------------------------------------------------------------
// K1: x_l = nf@W_l+b_l ; x_r = nf@W_r+b_r ; ident = LN(nf@res_W+res_b)*g+beta
// 32 nodes per block, 256 threads. A staged transposed [feat][node] stride 33.
// ---------------------------------------------------------------------------
__global__ __launch_bounds__(256) void k1_node_transform(
    const float* __restrict__ nf,
    const float* __restrict__ W_l, const float* __restrict__ b_l,
    const float* __restrict__ W_r, const float* __restrict__ b_r,
    const float* __restrict__ res_W, const float* __restrict__ res_b,
    const float* __restrict__ res_g, const float* __restrict__ res_beta,
    float* __restrict__ x_l, float* __restrict__ x_r, float* __restrict__ ident)
{
    __shared__ float As[64 * 33];
    __shared__ float Ws[64 * 128];
    const int tid = threadIdx.x;
    const int node0 = blockIdx.x * 32;

    for (int i = tid; i < 32 * 64; i += 256) {
        int n = i >> 6, cfe = i & 63;
        int gn = node0 + n;
        As[cfe * 33 + n] = (gn < NN) ? nf[gn * 64 + cfe] : 0.f;
    }
    const int nc = tid & 31, ng = tid >> 5;
    const int c0 = nc * 4, n4 = ng * 4;
    const float* const Wm[3] = {W_l, W_r, res_W};
    const float* const bm[3] = {b_l, b_r, res_b};
    float* const om[2] = {x_l, x_r};

    for (int p = 0; p < 3; ++p) {
        __syncthreads();
        for (int i = tid; i < 2048; i += 256)
            *(float4*)(Ws + i * 4) = *(const float4*)(Wm[p] + i * 4);
        __syncthreads();
        float acc[4][4];
        #pragma unroll
        for (int r = 0; r < 4; ++r) {
            acc[r][0] = 0.f; acc[r][1] = 0.f; acc[r][2] = 0.f; acc[r][3] = 0.f;
        }
        for (int k = 0; k < 64; ++k) {
            float4 w = *(const float4*)(Ws + k * 128 + c0);
            #pragma unroll
            for (int r = 0; r < 4; ++r) {
                float a = As[k * 33 + n4 + r];
                acc[r][0] += a * w.x; acc[r][1] += a * w.y;
                acc[r][2] += a * w.z; acc[r][3] += a * w.w;
            }
        }
        float4 bia = *(const float4*)(bm[p] + c0);
        if (p < 2) {
            float* out = om[p];
            #pragma unroll
            for (int r = 0; r < 4; ++r) {
                int gn = node0 + n4 + r;
                if (gn < NN) {
                    float4 v = make_float4(acc[r][0] + bia.x, acc[r][1] + bia.y,
                                           acc[r][2] + bia.z, acc[r][3] + bia.w);
                    *(float4*)(out + gn * 128 + c0) = v;
                }
            }
        } else {
            float4 g  = *(const float4*)(res_g + c0);
            float4 be = *(const float4*)(res_beta + c0);
            #pragma unroll
            for (int r = 0; r < 4; ++r) {
                float v0 = acc[r][0] + bia.x, v1 = acc[r][1] + bia.y;
                float v2 = acc[r][2] + bia.z, v3 = acc[r][3] + bia.w;
                float s = v0 + v1 + v2 + v3;
                float q = v0*v0 + v1*v1 + v2*v2 + v3*v3;
                #pragma unroll
                for (int m = 16; m >= 1; m >>= 1) {
                    s += __shfl_xor(s, m, 64);
                    q += __shfl_xor(q, m, 64);
                }
                float mean = s * (1.f / 128.f);
                float var  = q * (1.f / 128.f) - mean * mean;
                float inv  = rsqrtf(var + 1e-5f);
                int gn = node0 + n4 + r;
                if (gn < NN) {
                    float4 v = make_float4((v0 - mean) * inv * g.x + be.x,
                                           (v1 - mean) * inv * g.y + be.y,
                                           (v2 - mean) * inv * g.z + be.z,
                                           (v3 - mean) * inv * g.w + be.w);
                    *(float4*)(ident + gn * 128 + c0) = v;
                }
            }
        }
    }
}

// ---------------------------------------------------------------------------
// K2a: degree count only.
// ---------------------------------------------------------------------------
__global__ __launch_bounds__(256) void k2a_degree(
    const int* __restrict__ eidx, int* __restrict__ deg)
{
    int e = blockIdx.x * 256 + threadIdx.x;
    if (e >= NE) return;
    atomicAdd(deg + eidx[NE + e], 1);
}

// ---------------------------------------------------------------------------
// K3: single-block exclusive scan of deg -> row_start (N+1) and cursor copy.
// ---------------------------------------------------------------------------
__global__ __launch_bounds__(256) void k3_scan(
    const int* __restrict__ deg, int* __restrict__ row_start, int* __restrict__ cursor)
{
    __shared__ int wsum[4];
    __shared__ int carry_s;
    const int tid = threadIdx.x;
    const int lane = tid & 63;
    const int wid = tid >> 6;
    if (tid == 0) carry_s = 0;
    __syncthreads();
    for (int base = 0; base < NN; base += 1024) {
        int i0 = base + tid * 4;
        int4 v = make_int4(0, 0, 0, 0);
        if (i0 + 3 < NN) {
            v = *(const int4*)(deg + i0);
        } else {
            if (i0 + 0 < NN) v.x = deg[i0 + 0];
            if (i0 + 1 < NN) v.y = deg[i0 + 1];
            if (i0 + 2 < NN) v.z = deg[i0 + 2];
            if (i0 + 3 < NN) v.w = deg[i0 + 3];
        }
        int tsum = v.x + v.y + v.z + v.w;
        int sc = tsum;
        #pragma unroll
        for (int m = 1; m < 64; m <<= 1) {
            int t = __shfl_up(sc, m, 64);
            if (lane >= m) sc += t;
        }
        if (lane == 63) wsum[wid] = sc;
        __syncthreads();
        int woff = carry_s;
        for (int w = 0; w < wid; ++w) woff += wsum[w];
        int e0 = woff + sc - tsum;
        int e1 = e0 + v.x, e2 = e1 + v.y, e3 = e2 + v.z;
        if (i0 + 0 < NN) { row_start[i0 + 0] = e0; cursor[i0 + 0] = e0; }
        if (i0 + 1 < NN) { row_start[i0 + 1] = e1; cursor[i0 + 1] = e1; }
        if (i0 + 2 < NN) { row_start[i0 + 2] = e2; cursor[i0 + 2] = e2; }
        if (i0 + 3 < NN) { row_start[i0 + 3] = e3; cursor[i0 + 3] = e3; }
        __syncthreads();
        if (tid == 0) carry_s += wsum[0] + wsum[1] + wsum[2] + wsum[3];
        __syncthreads();
    }
    if (threadIdx.x == 0) row_start[NN] = carry_s;
}

// ---------------------------------------------------------------------------
// K4: scatter (edge id, src id) pairs into dst-sorted CSR order (one int2).
// ---------------------------------------------------------------------------
__global__ __launch_bounds__(256) void k4_scatter(
    const int* __restrict__ eidx, int* __restrict__ cursor,
    int2* __restrict__ csr_es)
{
    int e = blockIdx.x * 256 + threadIdx.x;
    if (e >= NE) return;
    int dst = eidx[NE + e];
    int srcn = eidx[e];
    int pos = atomicAdd(cursor + dst, 1);
    csr_es[pos] = make_int2(e, srcn);
}

// ---------------------------------------------------------------------------
// K5: fused GATv2 attention + aggregation. One wave per node.
// Single-pass unnormalized softmax (logits ~N(0,0.2): exp cannot overflow).
// - W_e columns pinned in 32 VGPRs via asm fence (compiler was reloading them
//   from L1 each edge at R2, VGPR_Count=32 showed the spill-to-reload).
// - Row indices loaded 64-at-a-time coalesced, broadcast per edge via shfl.
// - 2-stage software pipeline: next edge's ef + x_l loads issued before
//   computing current edge -> >=2 edges of memory in flight per wave.
// ---------------------------------------------------------------------------
__global__ __launch_bounds__(256, 4) void k5_attn_aggregate(
    const int2* __restrict__ csr_es, const int* __restrict__ row_start,
    const float* __restrict__ ef, const float* __restrict__ W_e,
    const float* __restrict__ att,
    const float* __restrict__ x_l, const float* __restrict__ x_r,
    const float* __restrict__ gat_bias,
    float* __restrict__ gat_out)
{
    const int lane = threadIdx.x & 63;
    const int node = (blockIdx.x * 256 + threadIdx.x) >> 6;
    if (node >= NN) return;
    const int c = lane * 2;

    float2 we[16];
    #pragma unroll
    for (int k = 0; k < 16; ++k)
        we[k] = *(const float2*)(W_e + k * 128 + c);
    #pragma unroll
    for (int k = 0; k < 16; ++k)
        asm volatile("" : "+v"(we[k].x), "+v"(we[k].y));

    const float2 a2 = *(const float2*)(att + c);
    const float2 xr = *(const float2*)(x_r + node * 128 + c);
    const float4* __restrict__ ef4 = (const float4*)ef;

    const int s  = row_start[node];
    const int ep = row_start[node + 1];

    float den = 0.f, n0 = 0.f, n1 = 0.f;

    for (int base = s; base < ep; base += 64) {
        int cnt = ep - base; if (cnt > 64) cnt = 64;
        int2 es = csr_es[base + (lane < cnt ? lane : cnt - 1)];
        int eidr = es.x, srcr = es.y;

        int e0 = __shfl(eidr, 0, 64);
        int s0 = __shfl(srcr, 0, 64);
        float4 A = ef4[e0 * 4 + 0], B = ef4[e0 * 4 + 1];
        float4 C = ef4[e0 * 4 + 2], D = ef4[e0 * 4 + 3];
        float2 X = *(const float2*)(x_l + s0 * 128 + c);

        for (int i = 0; i < cnt; ++i) {
            float4 cA = A, cB = B, cC = C, cD = D;
            float2 cX = X;
            if (i + 1 < cnt) {
                int e1 = __shfl(eidr, i + 1, 64);
                int s1 = __shfl(srcr, i + 1, 64);
                A = ef4[e1 * 4 + 0]; B = ef4[e1 * 4 + 1];
                C = ef4[e1 * 4 + 2]; D = ef4[e1 * 4 + 3];
                X = *(const float2*)(x_l + s1 * 128 + c);
            }
            float evx, evy;
            evx  = cA.x * we[0].x;  evy  = cA.x * we[0].y;
            evx += cA.y * we[1].x;  evy += cA.y * we[1].y;
            evx += cA.z * we[2].x;  evy += cA.z * we[2].y;
            evx += cA.w * we[3].x;  evy += cA.w * we[3].y;
            evx += cB.x * we[4].x;  evy += cB.x * we[4].y;
            evx += cB.y * we[5].x;  evy += cB.y * we[5].y;
            evx += cB.z * we[6].x;  evy += cB.z * we[6].y;
            evx += cB.w * we[7].x;  evy += cB.w * we[7].y;
            evx += cC.x * we[8].x;  evy += cC.x * we[8].y;
            evx += cC.y * we[9].x;  evy += cC.y * we[9].y;
            evx += cC.z * we[10].x; evy += cC.z * we[10].y;
            evx += cC.w * we[11].x; evy += cC.w * we[11].y;
            evx += cD.x * we[12].x; evy += cD.x * we[12].y;
            evx += cD.y * we[13].x; evy += cD.y * we[13].y;
            evx += cD.z * we[14].x; evy += cD.z * we[14].y;
            evx += cD.w * we[15].x; evy += cD.w * we[15].y;

            float mx = cX.x + xr.x + evx;
            float my = cX.y + xr.y + evy;
            float lx = fmaxf(mx, 0.2f * mx);
            float ly = fmaxf(my, 0.2f * my);
            float p = lx * a2.x + ly * a2.y;
            p += __shfl_xor(p, 8, 64);
            p += __shfl_xor(p, 4, 64);
            p += __shfl_xor(p, 2, 64);
            p += __shfl_xor(p, 1, 64);
            float ev = __expf(p);
            den += ev;
            n0 += ev * cX.x;
            n1 += ev * cX.y;
        }
    }
    float rden = (den > 0.f) ? (1.f / den) : 0.f;
    float2 gb = *(const float2*)(gat_bias + c);
    float2 o; o.x = n0 * rden + gb.x; o.y = n1 * rden + gb.y;
    *(float2*)(gat_out + node * 128 + c) = o;
}

// ---------------------------------------------------------------------------
// K6: h = relu(LN(concat(nf,gat)@W0+b0)); h = relu(LN(h@W1+b1)); out = ident+h
// 32 nodes per block, k-tiled (BK=32) LDS GEMMs.
// ---------------------------------------------------------------------------
__global__ __launch_bounds__(256) void k6_mlp(
    const float* __restrict__ nf, const float* __restrict__ gat,
    const float* __restrict__ ident,
    const float* __restrict__ W0, const float* __restrict__ b0,
    const float* __restrict__ g0, const float* __restrict__ be0,
    const float* __restrict__ W1, const float* __restrict__ b1,
    const float* __restrict__ g1, const float* __restrict__ be1,
    float* __restrict__ out)
{
    __shared__ float As[192 * 33];
    __shared__ float Ws[32 * 128];
    __shared__ float Hs[128 * 33];
    const int tid = threadIdx.x;
    const int node0 = blockIdx.x * 32;

    for (int i = tid; i < 32 * 192; i += 256) {
        int n = i / 192, cc = i % 192;
        int gn = node0 + n;
        float v = 0.f;
        if (gn < NN) v = (cc < 64) ? nf[gn * 64 + cc] : gat[gn * 128 + (cc - 64)];
        As[cc * 33 + n] = v;
    }
    const int nc = tid & 31, ng = tid >> 5;
    const int c0 = nc * 4, n4 = ng * 4;

    float acc[4][4];
    #pragma unroll
    for (int r = 0; r < 4; ++r) {
        acc[r][0] = 0.f; acc[r][1] = 0.f; acc[r][2] = 0.f; acc[r][3] = 0.f;
    }
    __syncthreads();

    for (int kb = 0; kb < 6; ++kb) {
        for (int i = tid; i < 1024; i += 256)
            *(float4*)(Ws + i * 4) = *(const float4*)(W0 + kb * 4096 + i * 4);
        __syncthreads();
        for (int k = 0; k < 32; ++k) {
            float4 w = *(const float4*)(Ws + k * 128 + c0);
            int krow = (kb * 32 + k) * 33;
            #pragma unroll
            for (int r = 0; r < 4; ++r) {
                float a = As[krow + n4 + r];
                acc[r][0] += a * w.x; acc[r][1] += a * w.y;
                acc[r][2] += a * w.z; acc[r][3] += a * w.w;
            }
        }
        __syncthreads();
    }

    {
        float4 bb = *(const float4*)(b0 + c0);
        float4 gg = *(const float4*)(g0 + c0);
        float4 bt = *(const float4*)(be0 + c0);
        #pragma unroll
        for (int r = 0; r < 4; ++r) {
            float v0 = acc[r][0] + bb.x, v1 = acc[r][1] + bb.y;
            float v2 = acc[r][2] + bb.z, v3 = acc[r][3] + bb.w;
            float s = v0 + v1 + v2 + v3;
            float q = v0*v0 + v1*v1 + v2*v2 + v3*v3;
            #pragma unroll
            for (int m = 16; m >= 1; m >>= 1) {
                s += __shfl_xor(s, m, 64);
                q += __shfl_xor(q, m, 64);
            }
            float mean = s * (1.f / 128.f);
            float inv  = rsqrtf(q * (1.f / 128.f) - mean * mean + 1e-5f);
            int n = n4 + r;
            Hs[(c0 + 0) * 33 + n] = fmaxf((v0 - mean) * inv * gg.x + bt.x, 0.f);
            Hs[(c0 + 1) * 33 + n] = fmaxf((v1 - mean) * inv * gg.y + bt.y, 0.f);
            Hs[(c0 + 2) * 33 + n] = fmaxf((v2 - mean) * inv * gg.z + bt.z, 0.f);
            Hs[(c0 + 3) * 33 + n] = fmaxf((v3 - mean) * inv * gg.w + bt.w, 0.f);
            acc[r][0] = 0.f; acc[r][1] = 0.f; acc[r][2] = 0.f; acc[r][3] = 0.f;
        }
    }
    __syncthreads();

    for (int kb = 0; kb < 4; ++kb) {
        for (int i = tid; i < 1024; i += 256)
            *(float4*)(Ws + i * 4) = *(const float4*)(W1 + kb * 4096 + i * 4);
        __syncthreads();
        for (int k = 0; k < 32; ++k) {
            float4 w = *(const float4*)(Ws + k * 128 + c0);
            int krow = (kb * 32 + k) * 33;
            #pragma unroll
            for (int r = 0; r < 4; ++r) {
                float a = Hs[krow + n4 + r];
                acc[r][0] += a * w.x; acc[r][1] += a * w.y;
                acc[r][2] += a * w.z; acc[r][3] += a * w.w;
            }
        }
        __syncthreads();
    }

    {
        float4 bb = *(const float4*)(b1 + c0);
        float4 gg = *(const float4*)(g1 + c0);
        float4 bt = *(const float4*)(be1 + c0);
        #pragma unroll
        for (int r = 0; r < 4; ++r) {
            float v0 = acc[r][0] + bb.x, v1 = acc[r][1] + bb.y;
            float v2 = acc[r][2] + bb.z, v3 = acc[r][3] + bb.w;
            float s = v0 + v1 + v2 + v3;
            float q = v0*v0 + v1*v1 + v2*v2 + v3*v3;
            #pragma unroll
            for (int m = 16; m >= 1; m >>= 1) {
                s += __shfl_xor(s, m, 64);
                q += __shfl_xor(q, m, 64);
            }
            float mean = s * (1.f / 128.f);
            float inv  = rsqrtf(q * (1.f / 128.f) - mean * mean + 1e-5f);
            float h0 = fmaxf((v0 - mean) * inv * gg.x + bt.x, 0.f);
            float h1 = fmaxf((v1 - mean) * inv * gg.y + bt.y, 0.f);
            float h2 = fmaxf((v2 - mean) * inv * gg.z + bt.z, 0.f);
            float h3 = fmaxf((v3 - mean) * inv * gg.w + bt.w, 0.f);
            int gn = node0 + n4 + r;
            if (gn < NN) {
                float4 idv = *(const float4*)(ident + gn * 128 + c0);
                float4 v = make_float4(idv.x + h0, idv.y + h1, idv.z + h2, idv.w + h3);
                *(float4*)(out + gn * 128 + c0) = v;
            }
        }
    }
}

// ---------------------------------------------------------------------------
extern "C" void kernel_launch(void* const* d_in, const int* in_sizes, int n_in,
                              void* d_out, int out_size, void* d_ws, size_t ws_size,
                              hipStream_t stream)
{
    const float* nf       = (const float*)d_in[0];
    const float* ef       = (const float*)d_in[1];
    const int*   eidx     = (const int*)d_in[2];
    const float* W_l      = (const float*)d_in[3];
    const float* b_l      = (const float*)d_in[4];
    const float* W_r      = (const float*)d_in[5];
    const float* b_r      = (const float*)d_in[6];
    const float* W_e      = (const float*)d_in[7];
    const float* att      = (const float*)d_in[8];
    const float* gat_bias = (const float*)d_in[9];
    const float* res_W    = (const float*)d_in[10];
    const float* res_b    = (const float*)d_in[11];
    const float* res_g    = (const float*)d_in[12];
    const float* res_beta = (const float*)d_in[13];
    const float* W0       = (const float*)d_in[14];
    const float* b0       = (const float*)d_in[15];
    const float* g0       = (const float*)d_in[16];
    const float* beta0    = (const float*)d_in[17];
    const float* W1       = (const float*)d_in[18];
    const float* b1       = (const float*)d_in[19];
    const float* g1       = (const float*)d_in[20];
    const float* beta1    = (const float*)d_in[21];
    float* out = (float*)d_out;

    char* ws = (char*)d_ws;
    size_t off = 0;
    auto alloc = [&](size_t bytes) -> void* {
        void* p = ws + off;
        off += (bytes + 255) & ~(size_t)255;
        return p;
    };
    float* x_l     = (float*)alloc((size_t)NN * 128 * 4);
    float* x_r     = (float*)alloc((size_t)NN * 128 * 4);
    float* ident   = (float*)alloc((size_t)NN * 128 * 4);
    int* deg       = (int*)alloc((size_t)NN * 4);
    int* row_start = (int*)alloc((size_t)(NN + 1) * 4);
    int* cursor    = (int*)alloc((size_t)NN * 4);
    int2* csr_es   = (int2*)alloc((size_t)NE * 8);
    float* gat_out = (float*)alloc((size_t)NN * 128 * 4);

    hipMemsetAsync(deg, 0, (size_t)NN * 4, stream);

    k1_node_transform<<<(NN + 31) / 32, 256, 0, stream>>>(
        nf, W_l, b_l, W_r, b_r, res_W, res_b, res_g, res_beta, x_l, x_r, ident);

    k2a_degree<<<(NE + 255) / 256, 256, 0, stream>>>(eidx, deg);

    k3_scan<<<1, 256, 0, stream>>>(deg, row_start, cursor);

    k4_scatter<<<(NE + 255) / 256, 256, 0, stream>>>(eidx, cursor, csr_es);

    k5_attn_aggregate<<<(NN * 64 + 255) / 256, 256, 0, stream>>>(
        csr_es, row_start, ef, W_e, att, x_l, x_r, gat_bias, gat_out);

    k6_mlp<<<(NN + 31) / 32, 256, 0, stream>>>(
        nf, gat_out, ident, W0, b0, g0, beta0, W1, b1, g1, beta1, out);
}

// Round 4
// 558.214 us; speedup vs baseline: 1.4555x; 1.1750x over previous
//
#include <hip/hip_runtime.h>

#define NN 50000
#define NE 800000

__device__ __forceinline__ int rfl(int v) { return __builtin_amdgcn_readfirstlane(v); }

// sum across the 16 lanes of each head via DPP (full-rate VALU, no DS pipe)
__device__ __forceinline__ float dpp_reduce16(float p) {
    int t;
    t = __builtin_amdgcn_update_dpp(0, __float_as_int(p), 0xB1, 0xF, 0xF, false); // quad_perm(1,0,3,2)
    p += __int_as_float(t);
    t = __builtin_amdgcn_update_dpp(0, __float_as_int(p), 0x4E, 0xF, 0xF, false); // quad_perm(2,3,0,1)
    p += __int_as_float(t);
    t = __builtin_amdgcn_update_dpp(0, __float_as_int(p), 0x124, 0xF, 0xF, false); // row_ror:4
    p += __int_as_float(t);
    t = __builtin_amdgcn_update_dpp(0, __float_as_int(p), 0x128, 0xF, 0xF, false); // row_ror:8
    p += __int_as_float(t);
    return p;
}

// ---------------------------------------------------------------------------
// K1: x_l = nf@W_l+b_l ; x_r = nf@W_r+b_r ; ident = LN(nf@res_W+res_b)*g+beta
// ---------------------------------------------------------------------------
__global__ __launch_bounds__(256) void k1_node_transform(
    const float* __restrict__ nf,
    const float* __restrict__ W_l, const float* __restrict__ b_l,
    const float* __restrict__ W_r, const float* __restrict__ b_r,
    const float* __restrict__ res_W, const float* __restrict__ res_b,
    const float* __restrict__ res_g, const float* __restrict__ res_beta,
    float* __restrict__ x_l, float* __restrict__ x_r, float* __restrict__ ident)
{
    __shared__ float As[64 * 33];
    __shared__ float Ws[64 * 128];
    const int tid = threadIdx.x;
    const int node0 = blockIdx.x * 32;

    for (int i = tid; i < 32 * 64; i += 256) {
        int n = i >> 6, cfe = i & 63;
        int gn = node0 + n;
        As[cfe * 33 + n] = (gn < NN) ? nf[gn * 64 + cfe] : 0.f;
    }
    const int nc = tid & 31, ng = tid >> 5;
    const int c0 = nc * 4, n4 = ng * 4;
    const float* const Wm[3] = {W_l, W_r, res_W};
    const float* const bm[3] = {b_l, b_r, res_b};
    float* const om[2] = {x_l, x_r};

    for (int p = 0; p < 3; ++p) {
        __syncthreads();
        for (int i = tid; i < 2048; i += 256)
            *(float4*)(Ws + i * 4) = *(const float4*)(Wm[p] + i * 4);
        __syncthreads();
        float acc[4][4];
        #pragma unroll
        for (int r = 0; r < 4; ++r) {
            acc[r][0] = 0.f; acc[r][1] = 0.f; acc[r][2] = 0.f; acc[r][3] = 0.f;
        }
        for (int k = 0; k < 64; ++k) {
            float4 w = *(const float4*)(Ws + k * 128 + c0);
            #pragma unroll
            for (int r = 0; r < 4; ++r) {
                float a = As[k * 33 + n4 + r];
                acc[r][0] += a * w.x; acc[r][1] += a * w.y;
                acc[r][2] += a * w.z; acc[r][3] += a * w.w;
            }
        }
        float4 bia = *(const float4*)(bm[p] + c0);
        if (p < 2) {
            float* out = om[p];
            #pragma unroll
            for (int r = 0; r < 4; ++r) {
                int gn = node0 + n4 + r;
                if (gn < NN) {
                    float4 v = make_float4(acc[r][0] + bia.x, acc[r][1] + bia.y,
                                           acc[r][2] + bia.z, acc[r][3] + bia.w);
                    *(float4*)(out + gn * 128 + c0) = v;
                }
            }
        } else {
            float4 g  = *(const float4*)(res_g + c0);
            float4 be = *(const float4*)(res_beta + c0);
            #pragma unroll
            for (int r = 0; r < 4; ++r) {
                float v0 = acc[r][0] + bia.x, v1 = acc[r][1] + bia.y;
                float v2 = acc[r][2] + bia.z, v3 = acc[r][3] + bia.w;
                float s = v0 + v1 + v2 + v3;
                float q = v0*v0 + v1*v1 + v2*v2 + v3*v3;
                #pragma unroll
                for (int m = 16; m >= 1; m >>= 1) {
                    s += __shfl_xor(s, m, 64);
                    q += __shfl_xor(q, m, 64);
                }
                float mean = s * (1.f / 128.f);
                float var  = q * (1.f / 128.f) - mean * mean;
                float inv  = rsqrtf(var + 1e-5f);
                int gn = node0 + n4 + r;
                if (gn < NN) {
                    float4 v = make_float4((v0 - mean) * inv * g.x + be.x,
                                           (v1 - mean) * inv * g.y + be.y,
                                           (v2 - mean) * inv * g.z + be.z,
                                           (v3 - mean) * inv * g.w + be.w);
                    *(float4*)(ident + gn * 128 + c0) = v;
                }
            }
        }
    }
}

// ---------------------------------------------------------------------------
// K2a: degree count only.
// ---------------------------------------------------------------------------
__global__ __launch_bounds__(256) void k2a_degree(
    const int* __restrict__ eidx, int* __restrict__ deg)
{
    int e = blockIdx.x * 256 + threadIdx.x;
    if (e >= NE) return;
    atomicAdd(deg + eidx[NE + e], 1);
}

// ---------------------------------------------------------------------------
// K3: single-block (1024 threads) exclusive scan of deg -> row_start + cursor.
// ---------------------------------------------------------------------------
__global__ __launch_bounds__(1024) void k3_scan(
    const int* __restrict__ deg, int* __restrict__ row_start, int* __restrict__ cursor)
{
    __shared__ int wsum[16];
    __shared__ int carry_s;
    const int tid = threadIdx.x;
    const int lane = tid & 63;
    const int wid = tid >> 6;
    if (tid == 0) carry_s = 0;
    __syncthreads();
    for (int base = 0; base < NN; base += 4096) {
        int i0 = base + tid * 4;
        int4 v = make_int4(0, 0, 0, 0);
        if (i0 + 3 < NN) {
            v = *(const int4*)(deg + i0);
        } else {
            if (i0 + 0 < NN) v.x = deg[i0 + 0];
            if (i0 + 1 < NN) v.y = deg[i0 + 1];
            if (i0 + 2 < NN) v.z = deg[i0 + 2];
            if (i0 + 3 < NN) v.w = deg[i0 + 3];
        }
        int tsum = v.x + v.y + v.z + v.w;
        int sc = tsum;
        #pragma unroll
        for (int m = 1; m < 64; m <<= 1) {
            int t = __shfl_up(sc, m, 64);
            if (lane >= m) sc += t;
        }
        if (lane == 63) wsum[wid] = sc;
        __syncthreads();
        int woff = carry_s;
        for (int w = 0; w < wid; ++w) woff += wsum[w];
        int e0 = woff + sc - tsum;
        int e1 = e0 + v.x, e2 = e1 + v.y, e3 = e2 + v.z;
        if (i0 + 0 < NN) { row_start[i0 + 0] = e0; cursor[i0 + 0] = e0; }
        if (i0 + 1 < NN) { row_start[i0 + 1] = e1; cursor[i0 + 1] = e1; }
        if (i0 + 2 < NN) { row_start[i0 + 2] = e2; cursor[i0 + 2] = e2; }
        if (i0 + 3 < NN) { row_start[i0 + 3] = e3; cursor[i0 + 3] = e3; }
        __syncthreads();
        if (tid == 0) {
            int t = 0;
            #pragma unroll
            for (int w = 0; w < 16; ++w) t += wsum[w];
            carry_s += t;
        }
        __syncthreads();
    }
    if (threadIdx.x == 0) row_start[NN] = carry_s;
}

// ---------------------------------------------------------------------------
// K4: scatter (edge id, src id) pairs into dst-sorted CSR order (one int2).
// ---------------------------------------------------------------------------
__global__ __launch_bounds__(256) void k4_scatter(
    const int* __restrict__ eidx, int* __restrict__ cursor,
    int2* __restrict__ csr_es)
{
    int e = blockIdx.x * 256 + threadIdx.x;
    if (e >= NE) return;
    int dst = eidx[NE + e];
    int srcn = eidx[e];
    int pos = atomicAdd(cursor + dst, 1);
    csr_es[pos] = make_int2(e, srcn);
}

// ---------------------------------------------------------------------------
// K5: fused GATv2 attention + aggregation. One wave per node.
// All per-edge data except x_l[src] is wave-uniform: CSR pair and the whole
// 64B ef row go through the SCALAR pipe (readfirstlane -> s_load), e-transform
// FMAs are v_fmac v,s,v (1 sgpr operand). Logit reduce = 4 DPP adds (no DS).
// 1-deep software pipeline: next edge's scalars + x_l issued before compute.
// ---------------------------------------------------------------------------
__global__ __launch_bounds__(256, 6) void k5_attn_aggregate(
    const int2* __restrict__ csr_es, const int* __restrict__ row_start,
    const float* __restrict__ ef, const float* __restrict__ W_e,
    const float* __restrict__ att,
    const float* __restrict__ x_l, const float* __restrict__ x_r,
    const float* __restrict__ gat_bias,
    float* __restrict__ gat_out)
{
    const int lane = threadIdx.x & 63;
    const int node = (blockIdx.x * 256 + threadIdx.x) >> 6;
    if (node >= NN) return;
    const int c = lane * 2;

    float2 we[16];
    #pragma unroll
    for (int k = 0; k < 16; ++k)
        we[k] = *(const float2*)(W_e + k * 128 + c);
    #pragma unroll
    for (int k = 0; k < 16; ++k)
        asm volatile("" : "+v"(we[k].x), "+v"(we[k].y));

    const float2 a2 = *(const float2*)(att + c);
    const float2 xr = *(const float2*)(x_r + node * 128 + c);
    const float4* __restrict__ efq = (const float4*)ef;
    const float2* __restrict__ xlc = (const float2*)(x_l + c);

    const int sj  = rfl(row_start[node]);
    const int epj = rfl(row_start[node + 1]);

    float den = 0.f, n0 = 0.f, n1 = 0.f;

    if (sj < epj) {
        int2 es0 = csr_es[sj];
        int eid = rfl(es0.x), src = rfl(es0.y);
        float4 A = efq[eid * 4 + 0], B = efq[eid * 4 + 1];
        float4 C = efq[eid * 4 + 2], D = efq[eid * 4 + 3];
        float2 X = xlc[src * 64];

        for (int j = sj; j < epj; ++j) {
            float4 cA = A, cB = B, cC = C, cD = D;
            float2 cX = X;
            if (j + 1 < epj) {
                int2 es = csr_es[j + 1];
                int e1 = rfl(es.x), s1 = rfl(es.y);
                A = efq[e1 * 4 + 0]; B = efq[e1 * 4 + 1];
                C = efq[e1 * 4 + 2]; D = efq[e1 * 4 + 3];
                X = xlc[s1 * 64];
            }
            float evx = cX.x + xr.x;
            float evy = cX.y + xr.y;
            evx += cA.x * we[0].x;  evy += cA.x * we[0].y;
            evx += cA.y * we[1].x;  evy += cA.y * we[1].y;
            evx += cA.z * we[2].x;  evy += cA.z * we[2].y;
            evx += cA.w * we[3].x;  evy += cA.w * we[3].y;
            evx += cB.x * we[4].x;  evy += cB.x * we[4].y;
            evx += cB.y * we[5].x;  evy += cB.y * we[5].y;
            evx += cB.z * we[6].x;  evy += cB.z * we[6].y;
            evx += cB.w * we[7].x;  evy += cB.w * we[7].y;
            evx += cC.x * we[8].x;  evy += cC.x * we[8].y;
            evx += cC.y * we[9].x;  evy += cC.y * we[9].y;
            evx += cC.z * we[10].x; evy += cC.z * we[10].y;
            evx += cC.w * we[11].x; evy += cC.w * we[11].y;
            evx += cD.x * we[12].x; evy += cD.x * we[12].y;
            evx += cD.y * we[13].x; evy += cD.y * we[13].y;
            evx += cD.z * we[14].x; evy += cD.z * we[14].y;
            evx += cD.w * we[15].x; evy += cD.w * we[15].y;

            float lx = fmaxf(evx, 0.2f * evx);
            float ly = fmaxf(evy, 0.2f * evy);
            float p = lx * a2.x + ly * a2.y;
            p = dpp_reduce16(p);
            float ev = __expf(p);
            den += ev;
            n0 += ev * cX.x;
            n1 += ev * cX.y;
        }
    }
    float rden = (den > 0.f) ? (1.f / den) : 0.f;
    float2 gb = *(const float2*)(gat_bias + c);
    float2 o; o.x = n0 * rden + gb.x; o.y = n1 * rden + gb.y;
    *(float2*)(gat_out + node * 128 + c) = o;
}

// ---------------------------------------------------------------------------
// K6: h = relu(LN(concat(nf,gat)@W0+b0)); h = relu(LN(h@W1+b1)); out = ident+h
// ---------------------------------------------------------------------------
__global__ __launch_bounds__(256) void k6_mlp(
    const float* __restrict__ nf, const float* __restrict__ gat,
    const float* __restrict__ ident,
    const float* __restrict__ W0, const float* __restrict__ b0,
    const float* __restrict__ g0, const float* __restrict__ be0,
    const float* __restrict__ W1, const float* __restrict__ b1,
    const float* __restrict__ g1, const float* __restrict__ be1,
    float* __restrict__ out)
{
    __shared__ float As[192 * 33];
    __shared__ float Ws[32 * 128];
    __shared__ float Hs[128 * 33];
    const int tid = threadIdx.x;
    const int node0 = blockIdx.x * 32;

    for (int i = tid; i < 32 * 192; i += 256) {
        int n = i / 192, cc = i % 192;
        int gn = node0 + n;
        float v = 0.f;
        if (gn < NN) v = (cc < 64) ? nf[gn * 64 + cc] : gat[gn * 128 + (cc - 64)];
        As[cc * 33 + n] = v;
    }
    const int nc = tid & 31, ng = tid >> 5;
    const int c0 = nc * 4, n4 = ng * 4;

    float acc[4][4];
    #pragma unroll
    for (int r = 0; r < 4; ++r) {
        acc[r][0] = 0.f; acc[r][1] = 0.f; acc[r][2] = 0.f; acc[r][3] = 0.f;
    }
    __syncthreads();

    for (int kb = 0; kb < 6; ++kb) {
        for (int i = tid; i < 1024; i += 256)
            *(float4*)(Ws + i * 4) = *(const float4*)(W0 + kb * 4096 + i * 4);
        __syncthreads();
        for (int k = 0; k < 32; ++k) {
            float4 w = *(const float4*)(Ws + k * 128 + c0);
            int krow = (kb * 32 + k) * 33;
            #pragma unroll
            for (int r = 0; r < 4; ++r) {
                float a = As[krow + n4 + r];
                acc[r][0] += a * w.x; acc[r][1] += a * w.y;
                acc[r][2] += a * w.z; acc[r][3] += a * w.w;
            }
        }
        __syncthreads();
    }

    {
        float4 bb = *(const float4*)(b0 + c0);
        float4 gg = *(const float4*)(g0 + c0);
        float4 bt = *(const float4*)(be0 + c0);
        #pragma unroll
        for (int r = 0; r < 4; ++r) {
            float v0 = acc[r][0] + bb.x, v1 = acc[r][1] + bb.y;
            float v2 = acc[r][2] + bb.z, v3 = acc[r][3] + bb.w;
            float s = v0 + v1 + v2 + v3;
            float q = v0*v0 + v1*v1 + v2*v2 + v3*v3;
            #pragma unroll
            for (int m = 16; m >= 1; m >>= 1) {
                s += __shfl_xor(s, m, 64);
                q += __shfl_xor(q, m, 64);
            }
            float mean = s * (1.f / 128.f);
            float inv  = rsqrtf(q * (1.f / 128.f) - mean * mean + 1e-5f);
            int n = n4 + r;
            Hs[(c0 + 0) * 33 + n] = fmaxf((v0 - mean) * inv * gg.x + bt.x, 0.f);
            Hs[(c0 + 1) * 33 + n] = fmaxf((v1 - mean) * inv * gg.y + bt.y, 0.f);
            Hs[(c0 + 2) * 33 + n] = fmaxf((v2 - mean) * inv * gg.z + bt.z, 0.f);
            Hs[(c0 + 3) * 33 + n] = fmaxf((v3 - mean) * inv * gg.w + bt.w, 0.f);
            acc[r][0] = 0.f; acc[r][1] = 0.f; acc[r][2] = 0.f; acc[r][3] = 0.f;
        }
    }
    __syncthreads();

    for (int kb = 0; kb < 4; ++kb) {
        for (int i = tid; i < 1024; i += 256)
            *(float4*)(Ws + i * 4) = *(const float4*)(W1 + kb * 4096 + i * 4);
        __syncthreads();
        for (int k = 0; k < 32; ++k) {
            float4 w = *(const float4*)(Ws + k * 128 + c0);
            int krow = (kb * 32 + k) * 33;
            #pragma unroll
            for (int r = 0; r < 4; ++r) {
                float a = Hs[krow + n4 + r];
                acc[r][0] += a * w.x; acc[r][1] += a * w.y;
                acc[r][2] += a * w.z; acc[r][3] += a * w.w;
            }
        }
        __syncthreads();
    }

    {
        float4 bb = *(const float4*)(b1 + c0);
        float4 gg = *(const float4*)(g1 + c0);
        float4 bt = *(const float4*)(be1 + c0);
        #pragma unroll
        for (int r = 0; r < 4; ++r) {
            float v0 = acc[r][0] + bb.x, v1 = acc[r][1] + bb.y;
            float v2 = acc[r][2] + bb.z, v3 = acc[r][3] + bb.w;
            float s = v0 + v1 + v2 + v3;
            float q = v0*v0 + v1*v1 + v2*v2 + v3*v3;
            #pragma unroll
            for (int m = 16; m >= 1; m >>= 1) {
                s += __shfl_xor(s, m, 64);
                q += __shfl_xor(q, m, 64);
            }
            float mean = s * (1.f / 128.f);
            float inv  = rsqrtf(q * (1.f / 128.f) - mean * mean + 1e-5f);
            float h0 = fmaxf((v0 - mean) * inv * gg.x + bt.x, 0.f);
            float h1 = fmaxf((v1 - mean) * inv * gg.y + bt.y, 0.f);
            float h2 = fmaxf((v2 - mean) * inv * gg.z + bt.z, 0.f);
            float h3 = fmaxf((v3 - mean) * inv * gg.w + bt.w, 0.f);
            int gn = node0 + n4 + r;
            if (gn < NN) {
                float4 idv = *(const float4*)(ident + gn * 128 + c0);
                float4 v = make_float4(idv.x + h0, idv.y + h1, idv.z + h2, idv.w + h3);
                *(float4*)(out + gn * 128 + c0) = v;
            }
        }
    }
}

// ---------------------------------------------------------------------------
extern "C" void kernel_launch(void* const* d_in, const int* in_sizes, int n_in,
                              void* d_out, int out_size, void* d_ws, size_t ws_size,
                              hipStream_t stream)
{
    const float* nf       = (const float*)d_in[0];
    const float* ef       = (const float*)d_in[1];
    const int*   eidx     = (const int*)d_in[2];
    const float* W_l      = (const float*)d_in[3];
    const float* b_l      = (const float*)d_in[4];
    const float* W_r      = (const float*)d_in[5];
    const float* b_r      = (const float*)d_in[6];
    const float* W_e      = (const float*)d_in[7];
    const float* att      = (const float*)d_in[8];
    const float* gat_bias = (const float*)d_in[9];
    const float* res_W    = (const float*)d_in[10];
    const float* res_b    = (const float*)d_in[11];
    const float* res_g    = (const float*)d_in[12];
    const float* res_beta = (const float*)d_in[13];
    const float* W0       = (const float*)d_in[14];
    const float* b0       = (const float*)d_in[15];
    const float* g0       = (const float*)d_in[16];
    const float* beta0    = (const float*)d_in[17];
    const float* W1       = (const float*)d_in[18];
    const float* b1       = (const float*)d_in[19];
    const float* g1       = (const float*)d_in[20];
    const float* beta1    = (const float*)d_in[21];
    float* out = (float*)d_out;

    char* ws = (char*)d_ws;
    size_t off = 0;
    auto alloc = [&](size_t bytes) -> void* {
        void* p = ws + off;
        off += (bytes + 255) & ~(size_t)255;
        return p;
    };
    float* x_l     = (float*)alloc((size_t)NN * 128 * 4);
    float* x_r     = (float*)alloc((size_t)NN * 128 * 4);
    float* ident   = (float*)alloc((size_t)NN * 128 * 4);
    int* deg       = (int*)alloc((size_t)NN * 4);
    int* row_start = (int*)alloc((size_t)(NN + 1) * 4);
    int* cursor    = (int*)alloc((size_t)NN * 4);
    int2* csr_es   = (int2*)alloc((size_t)NE * 8);
    float* gat_out = (float*)alloc((size_t)NN * 128 * 4);

    hipMemsetAsync(deg, 0, (size_t)NN * 4, stream);

    k1_node_transform<<<(NN + 31) / 32, 256, 0, stream>>>(
        nf, W_l, b_l, W_r, b_r, res_W, res_b, res_g, res_beta, x_l, x_r, ident);

    k2a_degree<<<(NE + 255) / 256, 256, 0, stream>>>(eidx, deg);

    k3_scan<<<1, 1024, 0, stream>>>(deg, row_start, cursor);

    k4_scatter<<<(NE + 255) / 256, 256, 0, stream>>>(eidx, cursor, csr_es);

    k5_attn_aggregate<<<(NN * 64 + 255) / 256, 256, 0, stream>>>(
        csr_es, row_start, ef, W_e, att, x_l, x_r, gat_bias, gat_out);

    k6_mlp<<<(NN + 31) / 32, 256, 0, stream>>>(
        nf, gat_out, ident, W0, b0, g0, beta0, W1, b1, g1, beta1, out);
}

// Round 5
// 445.806 us; speedup vs baseline: 1.8225x; 1.2521x over previous
//
#include <hip/hip_runtime.h>

#define NN 50000
#define NE 800000

typedef __attribute__((ext_vector_type(8))) short bf16x8;
typedef __attribute__((ext_vector_type(4))) float f32x4;

__device__ __forceinline__ int rfl(int v) { return __builtin_amdgcn_readfirstlane(v); }

__device__ __forceinline__ unsigned short bfb(float x) {
    union { float f; unsigned u; } v; v.f = x;
    unsigned r = v.u + 0x7FFFu + ((v.u >> 16) & 1u);   // round-to-nearest-even
    return (unsigned short)(r >> 16);
}
__device__ __forceinline__ unsigned pkbf(float lo, float hi) {
    return ((unsigned)bfb(hi) << 16) | (unsigned)bfb(lo);
}

// sum across the 16 lanes of each head via DPP (full-rate VALU, no DS pipe)
__device__ __forceinline__ float dpp_reduce16(float p) {
    int t;
    t = __builtin_amdgcn_update_dpp(0, __float_as_int(p), 0xB1, 0xF, 0xF, false);
    p += __int_as_float(t);
    t = __builtin_amdgcn_update_dpp(0, __float_as_int(p), 0x4E, 0xF, 0xF, false);
    p += __int_as_float(t);
    t = __builtin_amdgcn_update_dpp(0, __float_as_int(p), 0x124, 0xF, 0xF, false);
    p += __int_as_float(t);
    t = __builtin_amdgcn_update_dpp(0, __float_as_int(p), 0x128, 0xF, 0xF, false);
    p += __int_as_float(t);
    return p;
}

// ---------------------------------------------------------------------------
// K0: transpose + bf16-convert all weight matrices once per launch.
// Wt*[n][k] layout so MFMA B-frags are contiguous 16B loads.
// ---------------------------------------------------------------------------
__global__ __launch_bounds__(256) void k0_prep(
    const float* __restrict__ W_l, const float* __restrict__ W_r,
    const float* __restrict__ res_W, const float* __restrict__ W0,
    const float* __restrict__ W1,
    unsigned short* __restrict__ Wtl, unsigned short* __restrict__ Wtr,
    unsigned short* __restrict__ Wtres, unsigned short* __restrict__ Wt0,
    unsigned short* __restrict__ Wt1)
{
    int t = blockIdx.x * 256 + threadIdx.x;
    if (t < 24576) { int n = t / 192, k = t - n * 192; Wt0[t] = bfb(W0[k * 128 + n]); }
    if (t < 16384) { int n = t >> 7, k = t & 127; Wt1[t] = bfb(W1[k * 128 + n]); }
    if (t < 8192) {
        int n = t >> 6, k = t & 63;
        Wtl[t]   = bfb(W_l[k * 128 + n]);
        Wtr[t]   = bfb(W_r[k * 128 + n]);
        Wtres[t] = bfb(res_W[k * 128 + n]);
    }
}

// ---------------------------------------------------------------------------
// K1 (MFMA): x_l = nf@W_l+b_l ; x_r = nf@W_r+b_r ; ident = LN(nf@res_W+res_b)
// 64 nodes/block, 4 waves; wave w owns rows 16w..16w+15 (M-partition).
// A staged bf16 in LDS [64][64+8pad]; B-frags = 16B global loads from Wt*.
// ---------------------------------------------------------------------------
__global__ __launch_bounds__(256, 4) void k1_node_transform(
    const float* __restrict__ nf,
    const unsigned short* __restrict__ Wtl, const float* __restrict__ b_l,
    const unsigned short* __restrict__ Wtr, const float* __restrict__ b_r,
    const unsigned short* __restrict__ Wtres, const float* __restrict__ res_b,
    const float* __restrict__ res_g, const float* __restrict__ res_beta,
    float* __restrict__ x_l, float* __restrict__ x_r, float* __restrict__ ident)
{
    __shared__ __align__(16) unsigned As32[64 * 36];
    const int tid = threadIdx.x;
    const int node0 = blockIdx.x * 64;

    for (int i = tid; i < 64 * 32; i += 256) {
        int n = i >> 5, c2 = i & 31;
        int gn = node0 + n;
        float2 v = make_float2(0.f, 0.f);
        if (gn < NN) v = *(const float2*)(nf + gn * 64 + 2 * c2);
        As32[n * 36 + c2] = pkbf(v.x, v.y);
    }
    __syncthreads();

    const int lane = tid & 63, w = tid >> 6;
    const int c = lane & 15, ko = lane >> 4;
    const unsigned short* As = (const unsigned short*)As32;
    bf16x8 a0 = *(const bf16x8*)(As + (w * 16 + c) * 72 + 0 * 32 + ko * 8);
    bf16x8 a1 = *(const bf16x8*)(As + (w * 16 + c) * 72 + 1 * 32 + ko * 8);
    const int lrow0 = node0 + w * 16 + 4 * ko;

    #pragma unroll
    for (int p = 0; p < 3; ++p) {
        const unsigned short* Wt = (p == 0) ? Wtl : (p == 1) ? Wtr : Wtres;
        f32x4 acc[8];
        #pragma unroll
        for (int nt = 0; nt < 8; ++nt) acc[nt] = f32x4{0.f, 0.f, 0.f, 0.f};
        #pragma unroll
        for (int nt = 0; nt < 8; ++nt) {
            bf16x8 bf0 = *(const bf16x8*)(Wt + (nt * 16 + c) * 64 + 0 * 32 + ko * 8);
            acc[nt] = __builtin_amdgcn_mfma_f32_16x16x32_bf16(a0, bf0, acc[nt], 0, 0, 0);
            bf16x8 bf1 = *(const bf16x8*)(Wt + (nt * 16 + c) * 64 + 1 * 32 + ko * 8);
            acc[nt] = __builtin_amdgcn_mfma_f32_16x16x32_bf16(a1, bf1, acc[nt], 0, 0, 0);
        }
        if (p < 2) {
            const float* bias = (p == 0) ? b_l : b_r;
            float* o = (p == 0) ? x_l : x_r;
            float bv[8];
            #pragma unroll
            for (int nt = 0; nt < 8; ++nt) bv[nt] = bias[nt * 16 + c];
            #pragma unroll
            for (int reg = 0; reg < 4; ++reg) {
                int row = lrow0 + reg;
                if (row < NN) {
                    #pragma unroll
                    for (int nt = 0; nt < 8; ++nt)
                        o[row * 128 + nt * 16 + c] = acc[nt][reg] + bv[nt];
                }
            }
        } else {
            float bv[8], gv[8], tv[8];
            #pragma unroll
            for (int nt = 0; nt < 8; ++nt) {
                bv[nt] = res_b[nt * 16 + c];
                gv[nt] = res_g[nt * 16 + c];
                tv[nt] = res_beta[nt * 16 + c];
            }
            #pragma unroll
            for (int reg = 0; reg < 4; ++reg) {
                float sum = 0.f, sq = 0.f, hv[8];
                #pragma unroll
                for (int nt = 0; nt < 8; ++nt) {
                    float v = acc[nt][reg] + bv[nt];
                    hv[nt] = v; sum += v; sq += v * v;
                }
                #pragma unroll
                for (int m = 1; m <= 8; m <<= 1) {
                    sum += __shfl_xor(sum, m, 64);
                    sq  += __shfl_xor(sq, m, 64);
                }
                float mean = sum * (1.f / 128.f);
                float inv  = rsqrtf(sq * (1.f / 128.f) - mean * mean + 1e-5f);
                int row = lrow0 + reg;
                if (row < NN) {
                    #pragma unroll
                    for (int nt = 0; nt < 8; ++nt)
                        ident[row * 128 + nt * 16 + c] =
                            (hv[nt] - mean) * inv * gv[nt] + tv[nt];
                }
            }
        }
    }
}

// ---------------------------------------------------------------------------
// K2a: degree count only.
// ---------------------------------------------------------------------------
__global__ __launch_bounds__(256) void k2a_degree(
    const int* __restrict__ eidx, int* __restrict__ deg)
{
    int e = blockIdx.x * 256 + threadIdx.x;
    if (e >= NE) return;
    atomicAdd(deg + eidx[NE + e], 1);
}

// ---------------------------------------------------------------------------
// K3: single-block (1024 threads) exclusive scan of deg -> row_start + cursor.
// ---------------------------------------------------------------------------
__global__ __launch_bounds__(1024) void k3_scan(
    const int* __restrict__ deg, int* __restrict__ row_start, int* __restrict__ cursor)
{
    __shared__ int wsum[16];
    __shared__ int carry_s;
    const int tid = threadIdx.x;
    const int lane = tid & 63;
    const int wid = tid >> 6;
    if (tid == 0) carry_s = 0;
    __syncthreads();
    for (int base = 0; base < NN; base += 4096) {
        int i0 = base + tid * 4;
        int4 v = make_int4(0, 0, 0, 0);
        if (i0 + 3 < NN) {
            v = *(const int4*)(deg + i0);
        } else {
            if (i0 + 0 < NN) v.x = deg[i0 + 0];
            if (i0 + 1 < NN) v.y = deg[i0 + 1];
            if (i0 + 2 < NN) v.z = deg[i0 + 2];
            if (i0 + 3 < NN) v.w = deg[i0 + 3];
        }
        int tsum = v.x + v.y + v.z + v.w;
        int sc = tsum;
        #pragma unroll
        for (int m = 1; m < 64; m <<= 1) {
            int t = __shfl_up(sc, m, 64);
            if (lane >= m) sc += t;
        }
        if (lane == 63) wsum[wid] = sc;
        __syncthreads();
        int woff = carry_s;
        for (int w = 0; w < wid; ++w) woff += wsum[w];
        int e0 = woff + sc - tsum;
        int e1 = e0 + v.x, e2 = e1 + v.y, e3 = e2 + v.z;
        if (i0 + 0 < NN) { row_start[i0 + 0] = e0; cursor[i0 + 0] = e0; }
        if (i0 + 1 < NN) { row_start[i0 + 1] = e1; cursor[i0 + 1] = e1; }
        if (i0 + 2 < NN) { row_start[i0 + 2] = e2; cursor[i0 + 2] = e2; }
        if (i0 + 3 < NN) { row_start[i0 + 3] = e3; cursor[i0 + 3] = e3; }
        __syncthreads();
        if (tid == 0) {
            int t = 0;
            #pragma unroll
            for (int w = 0; w < 16; ++w) t += wsum[w];
            carry_s += t;
        }
        __syncthreads();
    }
    if (threadIdx.x == 0) row_start[NN] = carry_s;
}

// ---------------------------------------------------------------------------
// K4: scatter (edge id, src id) pairs into dst-sorted CSR order (one int2).
// ---------------------------------------------------------------------------
__global__ __launch_bounds__(256) void k4_scatter(
    const int* __restrict__ eidx, int* __restrict__ cursor,
    int2* __restrict__ csr_es)
{
    int e = blockIdx.x * 256 + threadIdx.x;
    if (e >= NE) return;
    int dst = eidx[NE + e];
    int srcn = eidx[e];
    int pos = atomicAdd(cursor + dst, 1);
    csr_es[pos] = make_int2(e, srcn);
}

// ---------------------------------------------------------------------------
// K5: fused GATv2 attention + aggregation. One wave per node. (unchanged R4)
// ---------------------------------------------------------------------------
__global__ __launch_bounds__(256, 6) void k5_attn_aggregate(
    const int2* __restrict__ csr_es, const int* __restrict__ row_start,
    const float* __restrict__ ef, const float* __restrict__ W_e,
    const float* __restrict__ att,
    const float* __restrict__ x_l, const float* __restrict__ x_r,
    const float* __restrict__ gat_bias,
    float* __restrict__ gat_out)
{
    const int lane = threadIdx.x & 63;
    const int node = (blockIdx.x * 256 + threadIdx.x) >> 6;
    if (node >= NN) return;
    const int c = lane * 2;

    float2 we[16];
    #pragma unroll
    for (int k = 0; k < 16; ++k)
        we[k] = *(const float2*)(W_e + k * 128 + c);
    #pragma unroll
    for (int k = 0; k < 16; ++k)
        asm volatile("" : "+v"(we[k].x), "+v"(we[k].y));

    const float2 a2 = *(const float2*)(att + c);
    const float2 xr = *(const float2*)(x_r + node * 128 + c);
    const float4* __restrict__ efq = (const float4*)ef;
    const float2* __restrict__ xlc = (const float2*)(x_l + c);

    const int sj  = rfl(row_start[node]);
    const int epj = rfl(row_start[node + 1]);

    float den = 0.f, n0 = 0.f, n1 = 0.f;

    if (sj < epj) {
        int2 es0 = csr_es[sj];
        int eid = rfl(es0.x), src = rfl(es0.y);
        float4 A = efq[eid * 4 + 0], B = efq[eid * 4 + 1];
        float4 C = efq[eid * 4 + 2], D = efq[eid * 4 + 3];
        float2 X = xlc[src * 64];

        for (int j = sj; j < epj; ++j) {
            float4 cA = A, cB = B, cC = C, cD = D;
            float2 cX = X;
            if (j + 1 < epj) {
                int2 es = csr_es[j + 1];
                int e1 = rfl(es.x), s1 = rfl(es.y);
                A = efq[e1 * 4 + 0]; B = efq[e1 * 4 + 1];
                C = efq[e1 * 4 + 2]; D = efq[e1 * 4 + 3];
                X = xlc[s1 * 64];
            }
            float evx = cX.x + xr.x;
            float evy = cX.y + xr.y;
            evx += cA.x * we[0].x;  evy += cA.x * we[0].y;
            evx += cA.y * we[1].x;  evy += cA.y * we[1].y;
            evx += cA.z * we[2].x;  evy += cA.z * we[2].y;
            evx += cA.w * we[3].x;  evy += cA.w * we[3].y;
            evx += cB.x * we[4].x;  evy += cB.x * we[4].y;
            evx += cB.y * we[5].x;  evy += cB.y * we[5].y;
            evx += cB.z * we[6].x;  evy += cB.z * we[6].y;
            evx += cB.w * we[7].x;  evy += cB.w * we[7].y;
            evx += cC.x * we[8].x;  evy += cC.x * we[8].y;
            evx += cC.y * we[9].x;  evy += cC.y * we[9].y;
            evx += cC.z * we[10].x; evy += cC.z * we[10].y;
            evx += cC.w * we[11].x; evy += cC.w * we[11].y;
            evx += cD.x * we[12].x; evy += cD.x * we[12].y;
            evx += cD.y * we[13].x; evy += cD.y * we[13].y;
            evx += cD.z * we[14].x; evy += cD.z * we[14].y;
            evx += cD.w * we[15].x; evy += cD.w * we[15].y;

            float lx = fmaxf(evx, 0.2f * evx);
            float ly = fmaxf(evy, 0.2f * evy);
            float p = lx * a2.x + ly * a2.y;
            p = dpp_reduce16(p);
            float ev = __expf(p);
            den += ev;
            n0 += ev * cX.x;
            n1 += ev * cX.y;
        }
    }
    float rden = (den > 0.f) ? (1.f / den) : 0.f;
    float2 gb = *(const float2*)(gat_bias + c);
    float2 o; o.x = n0 * rden + gb.x; o.y = n1 * rden + gb.y;
    *(float2*)(gat_out + node * 128 + c) = o;
}

// ---------------------------------------------------------------------------
// K6 (MFMA): h = relu(LN(concat(nf,gat)@W0+b0)); h = relu(LN(h@W1+b1));
// out = ident + h. 64 nodes/block, wave w owns rows 16w..16w+15.
// A bf16 LDS [64][192+8pad]; H round-trips bf16 LDS (aliased, barriered);
// B-frags 16B global loads from prepped transposed bf16 weights.
// ---------------------------------------------------------------------------
__global__ __launch_bounds__(256, 4) void k6_mlp_mfma(
    const float* __restrict__ nf, const float* __restrict__ gat,
    const float* __restrict__ ident,
    const unsigned short* __restrict__ Wt0, const float* __restrict__ b0,
    const float* __restrict__ g0, const float* __restrict__ be0,
    const unsigned short* __restrict__ Wt1, const float* __restrict__ b1,
    const float* __restrict__ g1, const float* __restrict__ be1,
    float* __restrict__ out)
{
    __shared__ __align__(16) unsigned LDS[64 * 100];
    const int tid = threadIdx.x;
    const int node0 = blockIdx.x * 64;

    for (int i = tid; i < 64 * 96; i += 256) {
        int n = i / 96, c2 = i - n * 96;
        int gn = node0 + n;
        float2 v = make_float2(0.f, 0.f);
        if (gn < NN)
            v = (c2 < 32) ? *(const float2*)(nf + gn * 64 + 2 * c2)
                          : *(const float2*)(gat + gn * 128 + 2 * (c2 - 32));
        LDS[n * 100 + c2] = pkbf(v.x, v.y);
    }
    __syncthreads();

    const int lane = tid & 63, w = tid >> 6;
    const int c = lane & 15, ko = lane >> 4;
    const int lrow = w * 16 + 4 * ko;  // local row (+reg)

    f32x4 acc[8];
    #pragma unroll
    for (int nt = 0; nt < 8; ++nt) acc[nt] = f32x4{0.f, 0.f, 0.f, 0.f};

    #pragma unroll
    for (int kb = 0; kb < 6; ++kb) {
        bf16x8 a = *(const bf16x8*)((const unsigned short*)LDS +
                                    (w * 16 + c) * 200 + kb * 32 + ko * 8);
        #pragma unroll
        for (int nt = 0; nt < 8; ++nt) {
            bf16x8 b = *(const bf16x8*)(Wt0 + (nt * 16 + c) * 192 + kb * 32 + ko * 8);
            acc[nt] = __builtin_amdgcn_mfma_f32_16x16x32_bf16(a, b, acc[nt], 0, 0, 0);
        }
    }

    float bv[8], gv[8], tv[8];
    #pragma unroll
    for (int nt = 0; nt < 8; ++nt) {
        bv[nt] = b0[nt * 16 + c];
        gv[nt] = g0[nt * 16 + c];
        tv[nt] = be0[nt * 16 + c];
    }
    __syncthreads();  // all As reads done before Hs overwrites (aliased region)

    unsigned short* Hs = (unsigned short*)LDS;
    #pragma unroll
    for (int reg = 0; reg < 4; ++reg) {
        float sum = 0.f, sq = 0.f, hv[8];
        #pragma unroll
        for (int nt = 0; nt < 8; ++nt) {
            float v = acc[nt][reg] + bv[nt];
            hv[nt] = v; sum += v; sq += v * v;
        }
        #pragma unroll
        for (int m = 1; m <= 8; m <<= 1) {
            sum += __shfl_xor(sum, m, 64);
            sq  += __shfl_xor(sq, m, 64);
        }
        float mean = sum * (1.f / 128.f);
        float inv  = rsqrtf(sq * (1.f / 128.f) - mean * mean + 1e-5f);
        #pragma unroll
        for (int nt = 0; nt < 8; ++nt) {
            float h = fmaxf((hv[nt] - mean) * inv * gv[nt] + tv[nt], 0.f);
            Hs[(lrow + reg) * 136 + nt * 16 + c] = bfb(h);
        }
    }
    __syncthreads();  // Hs visible before GEMM2 reads

    #pragma unroll
    for (int nt = 0; nt < 8; ++nt) acc[nt] = f32x4{0.f, 0.f, 0.f, 0.f};
    #pragma unroll
    for (int kb = 0; kb < 4; ++kb) {
        bf16x8 a = *(const bf16x8*)((const unsigned short*)LDS +
                                    (w * 16 + c) * 136 + kb * 32 + ko * 8);
        #pragma unroll
        for (int nt = 0; nt < 8; ++nt) {
            bf16x8 b = *(const bf16x8*)(Wt1 + (nt * 16 + c) * 128 + kb * 32 + ko * 8);
            acc[nt] = __builtin_amdgcn_mfma_f32_16x16x32_bf16(a, b, acc[nt], 0, 0, 0);
        }
    }

    #pragma unroll
    for (int nt = 0; nt < 8; ++nt) {
        bv[nt] = b1[nt * 16 + c];
        gv[nt] = g1[nt * 16 + c];
        tv[nt] = be1[nt * 16 + c];
    }
    #pragma unroll
    for (int reg = 0; reg < 4; ++reg) {
        float sum = 0.f, sq = 0.f, hv[8];
        #pragma unroll
        for (int nt = 0; nt < 8; ++nt) {
            float v = acc[nt][reg] + bv[nt];
            hv[nt] = v; sum += v; sq += v * v;
        }
        #pragma unroll
        for (int m = 1; m <= 8; m <<= 1) {
            sum += __shfl_xor(sum, m, 64);
            sq  += __shfl_xor(sq, m, 64);
        }
        float mean = sum * (1.f / 128.f);
        float inv  = rsqrtf(sq * (1.f / 128.f) - mean * mean + 1e-5f);
        int row = node0 + lrow + reg;
        if (row < NN) {
            #pragma unroll
            for (int nt = 0; nt < 8; ++nt) {
                float h = fmaxf((hv[nt] - mean) * inv * gv[nt] + tv[nt], 0.f);
                int col = nt * 16 + c;
                out[row * 128 + col] = ident[row * 128 + col] + h;
            }
        }
    }
}

// ---------------------------------------------------------------------------
extern "C" void kernel_launch(void* const* d_in, const int* in_sizes, int n_in,
                              void* d_out, int out_size, void* d_ws, size_t ws_size,
                              hipStream_t stream)
{
    const float* nf       = (const float*)d_in[0];
    const float* ef       = (const float*)d_in[1];
    const int*   eidx     = (const int*)d_in[2];
    const float* W_l      = (const float*)d_in[3];
    const float* b_l      = (const float*)d_in[4];
    const float* W_r      = (const float*)d_in[5];
    const float* b_r      = (const float*)d_in[6];
    const float* W_e      = (const float*)d_in[7];
    const float* att      = (const float*)d_in[8];
    const float* gat_bias = (const float*)d_in[9];
    const float* res_W    = (const float*)d_in[10];
    const float* res_b    = (const float*)d_in[11];
    const float* res_g    = (const float*)d_in[12];
    const float* res_beta = (const float*)d_in[13];
    const float* W0       = (const float*)d_in[14];
    const float* b0       = (const float*)d_in[15];
    const float* g0       = (const float*)d_in[16];
    const float* beta0    = (const float*)d_in[17];
    const float* W1       = (const float*)d_in[18];
    const float* b1       = (const float*)d_in[19];
    const float* g1       = (const float*)d_in[20];
    const float* beta1    = (const float*)d_in[21];
    float* out = (float*)d_out;

    char* ws = (char*)d_ws;
    size_t off = 0;
    auto alloc = [&](size_t bytes) -> void* {
        void* p = ws + off;
        off += (bytes + 255) & ~(size_t)255;
        return p;
    };
    float* x_l     = (float*)alloc((size_t)NN * 128 * 4);
    float* x_r     = (float*)alloc((size_t)NN * 128 * 4);
    float* ident   = (float*)alloc((size_t)NN * 128 * 4);
    int* deg       = (int*)alloc((size_t)NN * 4);
    int* row_start = (int*)alloc((size_t)(NN + 1) * 4);
    int* cursor    = (int*)alloc((size_t)NN * 4);
    int2* csr_es   = (int2*)alloc((size_t)NE * 8);
    float* gat_out = (float*)alloc((size_t)NN * 128 * 4);
    unsigned short* Wtl   = (unsigned short*)alloc(8192 * 2);
    unsigned short* Wtr   = (unsigned short*)alloc(8192 * 2);
    unsigned short* Wtres = (unsigned short*)alloc(8192 * 2);
    unsigned short* Wt0   = (unsigned short*)alloc(24576 * 2);
    unsigned short* Wt1   = (unsigned short*)alloc(16384 * 2);

    hipMemsetAsync(deg, 0, (size_t)NN * 4, stream);

    k0_prep<<<96, 256, 0, stream>>>(W_l, W_r, res_W, W0, W1,
                                    Wtl, Wtr, Wtres, Wt0, Wt1);

    k1_node_transform<<<(NN + 63) / 64, 256, 0, stream>>>(
        nf, Wtl, b_l, Wtr, b_r, Wtres, res_b, res_g, res_beta, x_l, x_r, ident);

    k2a_degree<<<(NE + 255) / 256, 256, 0, stream>>>(eidx, deg);

    k3_scan<<<1, 1024, 0, stream>>>(deg, row_start, cursor);

    k4_scatter<<<(NE + 255) / 256, 256, 0, stream>>>(eidx, cursor, csr_es);

    k5_attn_aggregate<<<(NN * 64 + 255) / 256, 256, 0, stream>>>(
        csr_es, row_start, ef, W_e, att, x_l, x_r, gat_bias, gat_out);

    k6_mlp_mfma<<<(NN + 63) / 64, 256, 0, stream>>>(
        nf, gat_out, ident, Wt0, b0, g0, beta0, Wt1, b1, g1, beta1, out);
}

// Round 6
// 425.613 us; speedup vs baseline: 1.9090x; 1.0474x over previous
//
#include <hip/hip_runtime.h>

#define NN 50000
#define NE 800000
#define NB 196  // (NN+255)/256

typedef __attribute__((ext_vector_type(8))) short bf16x8;
typedef __attribute__((ext_vector_type(4))) float f32x4;

__device__ __forceinline__ int rfl(int v) { return __builtin_amdgcn_readfirstlane(v); }

__device__ __forceinline__ unsigned short bfb(float x) {
    union { float f; unsigned u; } v; v.f = x;
    unsigned r = v.u + 0x7FFFu + ((v.u >> 16) & 1u);
    return (unsigned short)(r >> 16);
}
__device__ __forceinline__ unsigned pkbf(float lo, float hi) {
    return ((unsigned)bfb(hi) << 16) | (unsigned)bfb(lo);
}

__device__ __forceinline__ float dpp_reduce16(float p) {
    int t;
    t = __builtin_amdgcn_update_dpp(0, __float_as_int(p), 0xB1, 0xF, 0xF, false);
    p += __int_as_float(t);
    t = __builtin_amdgcn_update_dpp(0, __float_as_int(p), 0x4E, 0xF, 0xF, false);
    p += __int_as_float(t);
    t = __builtin_amdgcn_update_dpp(0, __float_as_int(p), 0x124, 0xF, 0xF, false);
    p += __int_as_float(t);
    t = __builtin_amdgcn_update_dpp(0, __float_as_int(p), 0x128, 0xF, 0xF, false);
    p += __int_as_float(t);
    return p;
}

// ---------------------------------------------------------------------------
// K0: transpose + bf16-convert all weight matrices once per launch.
// ---------------------------------------------------------------------------
__global__ __launch_bounds__(256) void k0_prep(
    const float* __restrict__ W_l, const float* __restrict__ W_r,
    const float* __restrict__ res_W, const float* __restrict__ W0,
    const float* __restrict__ W1,
    unsigned short* __restrict__ Wtl, unsigned short* __restrict__ Wtr,
    unsigned short* __restrict__ Wtres, unsigned short* __restrict__ Wt0,
    unsigned short* __restrict__ Wt1)
{
    int t = blockIdx.x * 256 + threadIdx.x;
    if (t < 24576) { int n = t / 192, k = t - n * 192; Wt0[t] = bfb(W0[k * 128 + n]); }
    if (t < 16384) { int n = t >> 7, k = t & 127; Wt1[t] = bfb(W1[k * 128 + n]); }
    if (t < 8192) {
        int n = t >> 6, k = t & 63;
        Wtl[t]   = bfb(W_l[k * 128 + n]);
        Wtr[t]   = bfb(W_r[k * 128 + n]);
        Wtres[t] = bfb(res_W[k * 128 + n]);
    }
}

// ---------------------------------------------------------------------------
// K1 (MFMA): x_l, x_r, ident.  (unchanged R5)
// ---------------------------------------------------------------------------
__global__ __launch_bounds__(256, 4) void k1_node_transform(
    const float* __restrict__ nf,
    const unsigned short* __restrict__ Wtl, const float* __restrict__ b_l,
    const unsigned short* __restrict__ Wtr, const float* __restrict__ b_r,
    const unsigned short* __restrict__ Wtres, const float* __restrict__ res_b,
    const float* __restrict__ res_g, const float* __restrict__ res_beta,
    float* __restrict__ x_l, float* __restrict__ x_r, float* __restrict__ ident)
{
    __shared__ __align__(16) unsigned As32[64 * 36];
    const int tid = threadIdx.x;
    const int node0 = blockIdx.x * 64;

    for (int i = tid; i < 64 * 32; i += 256) {
        int n = i >> 5, c2 = i & 31;
        int gn = node0 + n;
        float2 v = make_float2(0.f, 0.f);
        if (gn < NN) v = *(const float2*)(nf + gn * 64 + 2 * c2);
        As32[n * 36 + c2] = pkbf(v.x, v.y);
    }
    __syncthreads();

    const int lane = tid & 63, w = tid >> 6;
    const int c = lane & 15, ko = lane >> 4;
    const unsigned short* As = (const unsigned short*)As32;
    bf16x8 a0 = *(const bf16x8*)(As + (w * 16 + c) * 72 + 0 * 32 + ko * 8);
    bf16x8 a1 = *(const bf16x8*)(As + (w * 16 + c) * 72 + 1 * 32 + ko * 8);
    const int lrow0 = node0 + w * 16 + 4 * ko;

    #pragma unroll
    for (int p = 0; p < 3; ++p) {
        const unsigned short* Wt = (p == 0) ? Wtl : (p == 1) ? Wtr : Wtres;
        f32x4 acc[8];
        #pragma unroll
        for (int nt = 0; nt < 8; ++nt) acc[nt] = f32x4{0.f, 0.f, 0.f, 0.f};
        #pragma unroll
        for (int nt = 0; nt < 8; ++nt) {
            bf16x8 bf0 = *(const bf16x8*)(Wt + (nt * 16 + c) * 64 + 0 * 32 + ko * 8);
            acc[nt] = __builtin_amdgcn_mfma_f32_16x16x32_bf16(a0, bf0, acc[nt], 0, 0, 0);
            bf16x8 bf1 = *(const bf16x8*)(Wt + (nt * 16 + c) * 64 + 1 * 32 + ko * 8);
            acc[nt] = __builtin_amdgcn_mfma_f32_16x16x32_bf16(a1, bf1, acc[nt], 0, 0, 0);
        }
        if (p < 2) {
            const float* bias = (p == 0) ? b_l : b_r;
            float* o = (p == 0) ? x_l : x_r;
            float bv[8];
            #pragma unroll
            for (int nt = 0; nt < 8; ++nt) bv[nt] = bias[nt * 16 + c];
            #pragma unroll
            for (int reg = 0; reg < 4; ++reg) {
                int row = lrow0 + reg;
                if (row < NN) {
                    #pragma unroll
                    for (int nt = 0; nt < 8; ++nt)
                        o[row * 128 + nt * 16 + c] = acc[nt][reg] + bv[nt];
                }
            }
        } else {
            float bv[8], gv[8], tv[8];
            #pragma unroll
            for (int nt = 0; nt < 8; ++nt) {
                bv[nt] = res_b[nt * 16 + c];
                gv[nt] = res_g[nt * 16 + c];
                tv[nt] = res_beta[nt * 16 + c];
            }
            #pragma unroll
            for (int reg = 0; reg < 4; ++reg) {
                float sum = 0.f, sq = 0.f, hv[8];
                #pragma unroll
                for (int nt = 0; nt < 8; ++nt) {
                    float v = acc[nt][reg] + bv[nt];
                    hv[nt] = v; sum += v; sq += v * v;
                }
                #pragma unroll
                for (int m = 1; m <= 8; m <<= 1) {
                    sum += __shfl_xor(sum, m, 64);
                    sq  += __shfl_xor(sq, m, 64);
                }
                float mean = sum * (1.f / 128.f);
                float inv  = rsqrtf(sq * (1.f / 128.f) - mean * mean + 1e-5f);
                int row = lrow0 + reg;
                if (row < NN) {
                    #pragma unroll
                    for (int nt = 0; nt < 8; ++nt)
                        ident[row * 128 + nt * 16 + c] =
                            (hv[nt] - mean) * inv * gv[nt] + tv[nt];
                }
            }
        }
    }
}

// ---------------------------------------------------------------------------
// K2a: degree count only.
// ---------------------------------------------------------------------------
__global__ __launch_bounds__(256) void k2a_degree(
    const int* __restrict__ eidx, int* __restrict__ deg)
{
    int e = blockIdx.x * 256 + threadIdx.x;
    if (e >= NE) return;
    atomicAdd(deg + eidx[NE + e], 1);
}

// ---------------------------------------------------------------------------
// K3 (multi-block scan): a) per-block sums  b) scan block sums  c) apply.
// ---------------------------------------------------------------------------
__global__ __launch_bounds__(256) void k3a_blocksum(
    const int* __restrict__ deg, int* __restrict__ bsum)
{
    __shared__ int ws[4];
    int i = blockIdx.x * 256 + threadIdx.x;
    int v = (i < NN) ? deg[i] : 0;
    #pragma unroll
    for (int m = 32; m >= 1; m >>= 1) v += __shfl_xor(v, m, 64);
    if ((threadIdx.x & 63) == 0) ws[threadIdx.x >> 6] = v;
    __syncthreads();
    if (threadIdx.x == 0) bsum[blockIdx.x] = ws[0] + ws[1] + ws[2] + ws[3];
}

__global__ __launch_bounds__(256) void k3b_scan_bsums(
    int* __restrict__ bsum, int* __restrict__ row_start)
{
    __shared__ int ws[4];
    const int tid = threadIdx.x, lane = tid & 63, wid = tid >> 6;
    int v = (tid < NB) ? bsum[tid] : 0;
    int sc = v;
    #pragma unroll
    for (int m = 1; m < 64; m <<= 1) {
        int t = __shfl_up(sc, m, 64);
        if (lane >= m) sc += t;
    }
    if (lane == 63) ws[wid] = sc;
    __syncthreads();
    int woff = 0;
    for (int w = 0; w < wid; ++w) woff += ws[w];
    int incl = sc + woff;
    if (tid < NB) bsum[tid] = incl - v;          // exclusive
    if (tid == 255) row_start[NN] = incl;        // total (tails are zero)
}

__global__ __launch_bounds__(256) void k3c_apply(
    const int* __restrict__ deg, const int* __restrict__ bsum,
    int* __restrict__ row_start, int* __restrict__ cursor)
{
    __shared__ int ws[4];
    const int tid = threadIdx.x, lane = tid & 63, wid = tid >> 6;
    int i = blockIdx.x * 256 + tid;
    int v = (i < NN) ? deg[i] : 0;
    int sc = v;
    #pragma unroll
    for (int m = 1; m < 64; m <<= 1) {
        int t = __shfl_up(sc, m, 64);
        if (lane >= m) sc += t;
    }
    if (lane == 63) ws[wid] = sc;
    __syncthreads();
    int woff = bsum[blockIdx.x];
    for (int w = 0; w < wid; ++w) woff += ws[w];
    int excl = woff + sc - v;
    if (i < NN) { row_start[i] = excl; cursor[i] = excl; }
}

// ---------------------------------------------------------------------------
// K4: scatter (edge id, src id) pairs into dst-sorted CSR order (one int2).
// ---------------------------------------------------------------------------
__global__ __launch_bounds__(256) void k4_scatter(
    const int* __restrict__ eidx, int* __restrict__ cursor,
    int2* __restrict__ csr_es)
{
    int e = blockIdx.x * 256 + threadIdx.x;
    if (e >= NE) return;
    int dst = eidx[NE + e];
    int srcn = eidx[e];
    int pos = atomicAdd(cursor + dst, 1);
    csr_es[pos] = make_int2(e, srcn);
}

// ---------------------------------------------------------------------------
// K5: fused GATv2 attention + aggregation. One wave per node.
// W_e values pinned in VGPRs with an IN-LOOP asm fence: R5's one-shot pin was
// defeated (VGPR_Count=28 => 16 reloads/edge). The in-loop "+v" makes any
// spill require a reload before every iteration, forcing residency.
// ---------------------------------------------------------------------------
__global__ __launch_bounds__(256, 4) void k5_attn_aggregate(
    const int2* __restrict__ csr_es, const int* __restrict__ row_start,
    const float* __restrict__ ef, const float* __restrict__ W_e,
    const float* __restrict__ att,
    const float* __restrict__ x_l, const float* __restrict__ x_r,
    const float* __restrict__ gat_bias,
    float* __restrict__ gat_out)
{
    const int lane = threadIdx.x & 63;
    const int node = (blockIdx.x * 256 + threadIdx.x) >> 6;
    if (node >= NN) return;
    const int c = lane * 2;

    float wx[16], wy[16];
    #pragma unroll
    for (int k = 0; k < 16; ++k) {
        float2 t = *(const float2*)(W_e + k * 128 + c);
        wx[k] = t.x; wy[k] = t.y;
    }

    const float2 a2 = *(const float2*)(att + c);
    const float2 xr = *(const float2*)(x_r + node * 128 + c);
    const float4* __restrict__ efq = (const float4*)ef;
    const float2* __restrict__ xlc = (const float2*)(x_l + c);

    const int sj  = rfl(row_start[node]);
    const int epj = rfl(row_start[node + 1]);

    float den = 0.f, n0 = 0.f, n1 = 0.f;

    if (sj < epj) {
        int2 es0 = csr_es[sj];
        int eid = rfl(es0.x), src = rfl(es0.y);
        float4 A = efq[eid * 4 + 0], B = efq[eid * 4 + 1];
        float4 C = efq[eid * 4 + 2], D = efq[eid * 4 + 3];
        float2 X = xlc[src * 64];

        for (int j = sj; j < epj; ++j) {
            asm volatile("" : "+v"(wx[0]), "+v"(wx[1]), "+v"(wx[2]), "+v"(wx[3]),
                              "+v"(wx[4]), "+v"(wx[5]), "+v"(wx[6]), "+v"(wx[7]),
                              "+v"(wx[8]), "+v"(wx[9]), "+v"(wx[10]), "+v"(wx[11]),
                              "+v"(wx[12]), "+v"(wx[13]), "+v"(wx[14]), "+v"(wx[15]));
            asm volatile("" : "+v"(wy[0]), "+v"(wy[1]), "+v"(wy[2]), "+v"(wy[3]),
                              "+v"(wy[4]), "+v"(wy[5]), "+v"(wy[6]), "+v"(wy[7]),
                              "+v"(wy[8]), "+v"(wy[9]), "+v"(wy[10]), "+v"(wy[11]),
                              "+v"(wy[12]), "+v"(wy[13]), "+v"(wy[14]), "+v"(wy[15]));
            float4 cA = A, cB = B, cC = C, cD = D;
            float2 cX = X;
            if (j + 1 < epj) {
                int2 es = csr_es[j + 1];
                int e1 = rfl(es.x), s1 = rfl(es.y);
                A = efq[e1 * 4 + 0]; B = efq[e1 * 4 + 1];
                C = efq[e1 * 4 + 2]; D = efq[e1 * 4 + 3];
                X = xlc[s1 * 64];
            }
            float evx = cX.x + xr.x;
            float evy = cX.y + xr.y;
            evx += cA.x * wx[0];  evy += cA.x * wy[0];
            evx += cA.y * wx[1];  evy += cA.y * wy[1];
            evx += cA.z * wx[2];  evy += cA.z * wy[2];
            evx += cA.w * wx[3];  evy += cA.w * wy[3];
            evx += cB.x * wx[4];  evy += cB.x * wy[4];
            evx += cB.y * wx[5];  evy += cB.y * wy[5];
            evx += cB.z * wx[6];  evy += cB.z * wy[6];
            evx += cB.w * wx[7];  evy += cB.w * wy[7];
            evx += cC.x * wx[8];  evy += cC.x * wy[8];
            evx += cC.y * wx[9];  evy += cC.y * wy[9];
            evx += cC.z * wx[10]; evy += cC.z * wy[10];
            evx += cC.w * wx[11]; evy += cC.w * wy[11];
            evx += cD.x * wx[12]; evy += cD.x * wy[12];
            evx += cD.y * wx[13]; evy += cD.y * wy[13];
            evx += cD.z * wx[14]; evy += cD.z * wy[14];
            evx += cD.w * wx[15]; evy += cD.w * wy[15];

            float lx = fmaxf(evx, 0.2f * evx);
            float ly = fmaxf(evy, 0.2f * evy);
            float p = lx * a2.x + ly * a2.y;
            p = dpp_reduce16(p);
            float ev = __expf(p);
            den += ev;
            n0 += ev * cX.x;
            n1 += ev * cX.y;
        }
    }
    float rden = (den > 0.f) ? (1.f / den) : 0.f;
    float2 gb = *(const float2*)(gat_bias + c);
    float2 o; o.x = n0 * rden + gb.x; o.y = n1 * rden + gb.y;
    *(float2*)(gat_out + node * 128 + c) = o;
}

// ---------------------------------------------------------------------------
// K6 (MFMA): MLP + LN + residual add.  (unchanged R5)
// ---------------------------------------------------------------------------
__global__ __launch_bounds__(256, 4) void k6_mlp_mfma(
    const float* __restrict__ nf, const float* __restrict__ gat,
    const float* __restrict__ ident,
    const unsigned short* __restrict__ Wt0, const float* __restrict__ b0,
    const float* __restrict__ g0, const float* __restrict__ be0,
    const unsigned short* __restrict__ Wt1, const float* __restrict__ b1,
    const float* __restrict__ g1, const float* __restrict__ be1,
    float* __restrict__ out)
{
    __shared__ __align__(16) unsigned LDS[64 * 100];
    const int tid = threadIdx.x;
    const int node0 = blockIdx.x * 64;

    for (int i = tid; i < 64 * 96; i += 256) {
        int n = i / 96, c2 = i - n * 96;
        int gn = node0 + n;
        float2 v = make_float2(0.f, 0.f);
        if (gn < NN)
            v = (c2 < 32) ? *(const float2*)(nf + gn * 64 + 2 * c2)
                          : *(const float2*)(gat + gn * 128 + 2 * (c2 - 32));
        LDS[n * 100 + c2] = pkbf(v.x, v.y);
    }
    __syncthreads();

    const int lane = tid & 63, w = tid >> 6;
    const int c = lane & 15, ko = lane >> 4;
    const int lrow = w * 16 + 4 * ko;

    f32x4 acc[8];
    #pragma unroll
    for (int nt = 0; nt < 8; ++nt) acc[nt] = f32x4{0.f, 0.f, 0.f, 0.f};

    #pragma unroll
    for (int kb = 0; kb < 6; ++kb) {
        bf16x8 a = *(const bf16x8*)((const unsigned short*)LDS +
                                    (w * 16 + c) * 200 + kb * 32 + ko * 8);
        #pragma unroll
        for (int nt = 0; nt < 8; ++nt) {
            bf16x8 b = *(const bf16x8*)(Wt0 + (nt * 16 + c) * 192 + kb * 32 + ko * 8);
            acc[nt] = __builtin_amdgcn_mfma_f32_16x16x32_bf16(a, b, acc[nt], 0, 0, 0);
        }
    }

    float bv[8], gv[8], tv[8];
    #pragma unroll
    for (int nt = 0; nt < 8; ++nt) {
        bv[nt] = b0[nt * 16 + c];
        gv[nt] = g0[nt * 16 + c];
        tv[nt] = be0[nt * 16 + c];
    }
    __syncthreads();

    unsigned short* Hs = (unsigned short*)LDS;
    #pragma unroll
    for (int reg = 0; reg < 4; ++reg) {
        float sum = 0.f, sq = 0.f, hv[8];
        #pragma unroll
        for (int nt = 0; nt < 8; ++nt) {
            float v = acc[nt][reg] + bv[nt];
            hv[nt] = v; sum += v; sq += v * v;
        }
        #pragma unroll
        for (int m = 1; m <= 8; m <<= 1) {
            sum += __shfl_xor(sum, m, 64);
            sq  += __shfl_xor(sq, m, 64);
        }
        float mean = sum * (1.f / 128.f);
        float inv  = rsqrtf(sq * (1.f / 128.f) - mean * mean + 1e-5f);
        #pragma unroll
        for (int nt = 0; nt < 8; ++nt) {
            float h = fmaxf((hv[nt] - mean) * inv * gv[nt] + tv[nt], 0.f);
            Hs[(lrow + reg) * 136 + nt * 16 + c] = bfb(h);
        }
    }
    __syncthreads();

    #pragma unroll
    for (int nt = 0; nt < 8; ++nt) acc[nt] = f32x4{0.f, 0.f, 0.f, 0.f};
    #pragma unroll
    for (int kb = 0; kb < 4; ++kb) {
        bf16x8 a = *(const bf16x8*)((const unsigned short*)LDS +
                                    (w * 16 + c) * 136 + kb * 32 + ko * 8);
        #pragma unroll
        for (int nt = 0; nt < 8; ++nt) {
            bf16x8 b = *(const bf16x8*)(Wt1 + (nt * 16 + c) * 128 + kb * 32 + ko * 8);
            acc[nt] = __builtin_amdgcn_mfma_f32_16x16x32_bf16(a, b, acc[nt], 0, 0, 0);
        }
    }

    #pragma unroll
    for (int nt = 0; nt < 8; ++nt) {
        bv[nt] = b1[nt * 16 + c];
        gv[nt] = g1[nt * 16 + c];
        tv[nt] = be1[nt * 16 + c];
    }
    #pragma unroll
    for (int reg = 0; reg < 4; ++reg) {
        float sum = 0.f, sq = 0.f, hv[8];
        #pragma unroll
        for (int nt = 0; nt < 8; ++nt) {
            float v = acc[nt][reg] + bv[nt];
            hv[nt] = v; sum += v; sq += v * v;
        }
        #pragma unroll
        for (int m = 1; m <= 8; m <<= 1) {
            sum += __shfl_xor(sum, m, 64);
            sq  += __shfl_xor(sq, m, 64);
        }
        float mean = sum * (1.f / 128.f);
        float inv  = rsqrtf(sq * (1.f / 128.f) - mean * mean + 1e-5f);
        int row = node0 + lrow + reg;
        if (row < NN) {
            #pragma unroll
            for (int nt = 0; nt < 8; ++nt) {
                float h = fmaxf((hv[nt] - mean) * inv * gv[nt] + tv[nt], 0.f);
                int col = nt * 16 + c;
                out[row * 128 + col] = ident[row * 128 + col] + h;
            }
        }
    }
}

// ---------------------------------------------------------------------------
extern "C" void kernel_launch(void* const* d_in, const int* in_sizes, int n_in,
                              void* d_out, int out_size, void* d_ws, size_t ws_size,
                              hipStream_t stream)
{
    const float* nf       = (const float*)d_in[0];
    const float* ef       = (const float*)d_in[1];
    const int*   eidx     = (const int*)d_in[2];
    const float* W_l      = (const float*)d_in[3];
    const float* b_l      = (const float*)d_in[4];
    const float* W_r      = (const float*)d_in[5];
    const float* b_r      = (const float*)d_in[6];
    const float* W_e      = (const float*)d_in[7];
    const float* att      = (const float*)d_in[8];
    const float* gat_bias = (const float*)d_in[9];
    const float* res_W    = (const float*)d_in[10];
    const float* res_b    = (const float*)d_in[11];
    const float* res_g    = (const float*)d_in[12];
    const float* res_beta = (const float*)d_in[13];
    const float* W0       = (const float*)d_in[14];
    const float* b0       = (const float*)d_in[15];
    const float* g0       = (const float*)d_in[16];
    const float* beta0    = (const float*)d_in[17];
    const float* W1       = (const float*)d_in[18];
    const float* b1       = (const float*)d_in[19];
    const float* g1       = (const float*)d_in[20];
    const float* beta1    = (const float*)d_in[21];
    float* out = (float*)d_out;

    char* ws = (char*)d_ws;
    size_t off = 0;
    auto alloc = [&](size_t bytes) -> void* {
        void* p = ws + off;
        off += (bytes + 255) & ~(size_t)255;
        return p;
    };
    float* x_l     = (float*)alloc((size_t)NN * 128 * 4);
    float* x_r     = (float*)alloc((size_t)NN * 128 * 4);
    float* ident   = (float*)alloc((size_t)NN * 128 * 4);
    int* deg       = (int*)alloc((size_t)NN * 4);
    int* row_start = (int*)alloc((size_t)(NN + 1) * 4);
    int* cursor    = (int*)alloc((size_t)NN * 4);
    int* bsum      = (int*)alloc((size_t)(NB + 1) * 4);
    int2* csr_es   = (int2*)alloc((size_t)NE * 8);
    float* gat_out = (float*)alloc((size_t)NN * 128 * 4);
    unsigned short* Wtl   = (unsigned short*)alloc(8192 * 2);
    unsigned short* Wtr   = (unsigned short*)alloc(8192 * 2);
    unsigned short* Wtres = (unsigned short*)alloc(8192 * 2);
    unsigned short* Wt0   = (unsigned short*)alloc(24576 * 2);
    unsigned short* Wt1   = (unsigned short*)alloc(16384 * 2);

    hipMemsetAsync(deg, 0, (size_t)NN * 4, stream);

    k0_prep<<<96, 256, 0, stream>>>(W_l, W_r, res_W, W0, W1,
                                    Wtl, Wtr, Wtres, Wt0, Wt1);

    k1_node_transform<<<(NN + 63) / 64, 256, 0, stream>>>(
        nf, Wtl, b_l, Wtr, b_r, Wtres, res_b, res_g, res_beta, x_l, x_r, ident);

    k2a_degree<<<(NE + 255) / 256, 256, 0, stream>>>(eidx, deg);

    k3a_blocksum<<<NB, 256, 0, stream>>>(deg, bsum);
    k3b_scan_bsums<<<1, 256, 0, stream>>>(bsum, row_start);
    k3c_apply<<<NB, 256, 0, stream>>>(deg, bsum, row_start, cursor);

    k4_scatter<<<(NE + 255) / 256, 256, 0, stream>>>(eidx, cursor, csr_es);

    k5_attn_aggregate<<<(NN * 64 + 255) / 256, 256, 0, stream>>>(
        csr_es, row_start, ef, W_e, att, x_l, x_r, gat_bias, gat_out);

    k6_mlp_mfma<<<(NN + 63) / 64, 256, 0, stream>>>(
        nf, gat_out, ident, Wt0, b0, g0, beta0, Wt1, b1, g1, beta1, out);
}

// Round 8
// 395.143 us; speedup vs baseline: 2.0562x; 1.0771x over previous
//
#include <hip/hip_runtime.h>

#define NN 50000
#define NE 800000
#define NB 196   // (NN+255)/256
#define K1B 782  // (NN+63)/64

typedef __attribute__((ext_vector_type(8))) short bf16x8;
typedef __attribute__((ext_vector_type(4))) float f32x4;
typedef __attribute__((ext_vector_type(2))) _Float16 h2f;

__device__ __forceinline__ int rfl(int v) { return __builtin_amdgcn_readfirstlane(v); }

__device__ __forceinline__ unsigned short bfb(float x) {
    union { float f; unsigned u; } v; v.f = x;
    unsigned r = v.u + 0x7FFFu + ((v.u >> 16) & 1u);
    return (unsigned short)(r >> 16);
}
__device__ __forceinline__ unsigned pkbf(float lo, float hi) {
    return ((unsigned)bfb(hi) << 16) | (unsigned)bfb(lo);
}
__device__ __forceinline__ unsigned pkh2(float a, float b) {
    union { h2f h; unsigned u; } x;
    x.h.x = (_Float16)a; x.h.y = (_Float16)b;
    return x.u;
}
__device__ __forceinline__ float fdot2u(unsigned a, unsigned b, float c) {
    union { unsigned u; h2f h; } ua, ub; ua.u = a; ub.u = b;
    return __builtin_amdgcn_fdot2(ua.h, ub.h, c, false);
}

__device__ __forceinline__ float dpp_reduce16(float p) {
    int t;
    t = __builtin_amdgcn_update_dpp(0, __float_as_int(p), 0xB1, 0xF, 0xF, false);
    p += __int_as_float(t);
    t = __builtin_amdgcn_update_dpp(0, __float_as_int(p), 0x4E, 0xF, 0xF, false);
    p += __int_as_float(t);
    t = __builtin_amdgcn_update_dpp(0, __float_as_int(p), 0x124, 0xF, 0xF, false);
    p += __int_as_float(t);
    t = __builtin_amdgcn_update_dpp(0, __float_as_int(p), 0x128, 0xF, 0xF, false);
    p += __int_as_float(t);
    return p;
}

// ---------------------------------------------------------------------------
// K0 (mega-prep, one dispatch): bf16-transpose all weights, f16-pair ef and
// W_e, zero deg, and statically set row_start[NN]=NE.
// ---------------------------------------------------------------------------
__global__ __launch_bounds__(256) void k0_prep(
    const float* __restrict__ W_l, const float* __restrict__ W_r,
    const float* __restrict__ res_W, const float* __restrict__ W0,
    const float* __restrict__ W1, const float* __restrict__ W_e,
    const float* __restrict__ ef,
    unsigned short* __restrict__ Wtl, unsigned short* __restrict__ Wtr,
    unsigned short* __restrict__ Wtres, unsigned short* __restrict__ Wt0,
    unsigned short* __restrict__ Wt1,
    unsigned* __restrict__ Wep, unsigned* __restrict__ efp,
    int* __restrict__ deg, int* __restrict__ row_start)
{
    const int t0 = blockIdx.x * 256 + threadIdx.x;
    const int nth = gridDim.x * 256;
    for (int t = t0; t < NE * 8; t += nth) {
        float2 v = *(const float2*)(ef + 2 * t);
        efp[t] = pkh2(v.x, v.y);
    }
    if (t0 < 24576) { int n = t0 / 192, k = t0 - n * 192; Wt0[t0] = bfb(W0[k * 128 + n]); }
    if (t0 < 16384) { int n = t0 >> 7, k = t0 & 127; Wt1[t0] = bfb(W1[k * 128 + n]); }
    if (t0 < 8192) {
        int n = t0 >> 6, k = t0 & 63;
        Wtl[t0]   = bfb(W_l[k * 128 + n]);
        Wtr[t0]   = bfb(W_r[k * 128 + n]);
        Wtres[t0] = bfb(res_W[k * 128 + n]);
    }
    if (t0 < 1024) {  // Wep[c][j] = (W_e[2j][c], W_e[2j+1][c])
        int c = t0 >> 3, j = t0 & 7;
        Wep[t0] = pkh2(W_e[(2 * j) * 128 + c], W_e[(2 * j + 1) * 128 + c]);
    }
    if (t0 < NN) deg[t0] = 0;
    if (t0 == 0) row_start[NN] = NE;
}

// ---------------------------------------------------------------------------
// KA (fused): blocks [0,K1B) do the MFMA node transforms (x_l, x_r, ident);
// blocks [K1B, ...) do the degree count. Block-uniform branch.
// ---------------------------------------------------------------------------
__global__ __launch_bounds__(256, 4) void ka_nodes_degree(
    const float* __restrict__ nf,
    const unsigned short* __restrict__ Wtl, const float* __restrict__ b_l,
    const unsigned short* __restrict__ Wtr, const float* __restrict__ b_r,
    const unsigned short* __restrict__ Wtres, const float* __restrict__ res_b,
    const float* __restrict__ res_g, const float* __restrict__ res_beta,
    float* __restrict__ x_l, float* __restrict__ x_r, float* __restrict__ ident,
    const int* __restrict__ eidx, int* __restrict__ deg)
{
    if (blockIdx.x >= K1B) {
        int e = (blockIdx.x - K1B) * 256 + threadIdx.x;
        if (e < NE) atomicAdd(deg + eidx[NE + e], 1);
        return;
    }
    __shared__ __align__(16) unsigned As32[64 * 36];
    const int tid = threadIdx.x;
    const int node0 = blockIdx.x * 64;

    for (int i = tid; i < 64 * 32; i += 256) {
        int n = i >> 5, c2 = i & 31;
        int gn = node0 + n;
        float2 v = make_float2(0.f, 0.f);
        if (gn < NN) v = *(const float2*)(nf + gn * 64 + 2 * c2);
        As32[n * 36 + c2] = pkbf(v.x, v.y);
    }
    __syncthreads();

    const int lane = tid & 63, w = tid >> 6;
    const int c = lane & 15, ko = lane >> 4;
    const unsigned short* As = (const unsigned short*)As32;
    bf16x8 a0 = *(const bf16x8*)(As + (w * 16 + c) * 72 + 0 * 32 + ko * 8);
    bf16x8 a1 = *(const bf16x8*)(As + (w * 16 + c) * 72 + 1 * 32 + ko * 8);
    const int lrow0 = node0 + w * 16 + 4 * ko;

    #pragma unroll
    for (int p = 0; p < 3; ++p) {
        const unsigned short* Wt = (p == 0) ? Wtl : (p == 1) ? Wtr : Wtres;
        f32x4 acc[8];
        #pragma unroll
        for (int nt = 0; nt < 8; ++nt) acc[nt] = f32x4{0.f, 0.f, 0.f, 0.f};
        #pragma unroll
        for (int nt = 0; nt < 8; ++nt) {
            bf16x8 bf0 = *(const bf16x8*)(Wt + (nt * 16 + c) * 64 + 0 * 32 + ko * 8);
            acc[nt] = __builtin_amdgcn_mfma_f32_16x16x32_bf16(a0, bf0, acc[nt], 0, 0, 0);
            bf16x8 bf1 = *(const bf16x8*)(Wt + (nt * 16 + c) * 64 + 1 * 32 + ko * 8);
            acc[nt] = __builtin_amdgcn_mfma_f32_16x16x32_bf16(a1, bf1, acc[nt], 0, 0, 0);
        }
        if (p < 2) {
            const float* bias = (p == 0) ? b_l : b_r;
            float* o = (p == 0) ? x_l : x_r;
            float bv[8];
            #pragma unroll
            for (int nt = 0; nt < 8; ++nt) bv[nt] = bias[nt * 16 + c];
            #pragma unroll
            for (int reg = 0; reg < 4; ++reg) {
                int row = lrow0 + reg;
                if (row < NN) {
                    #pragma unroll
                    for (int nt = 0; nt < 8; ++nt)
                        o[row * 128 + nt * 16 + c] = acc[nt][reg] + bv[nt];
                }
            }
        } else {
            float bv[8], gv[8], tv[8];
            #pragma unroll
            for (int nt = 0; nt < 8; ++nt) {
                bv[nt] = res_b[nt * 16 + c];
                gv[nt] = res_g[nt * 16 + c];
                tv[nt] = res_beta[nt * 16 + c];
            }
            #pragma unroll
            for (int reg = 0; reg < 4; ++reg) {
                float sum = 0.f, sq = 0.f, hv[8];
                #pragma unroll
                for (int nt = 0; nt < 8; ++nt) {
                    float v = acc[nt][reg] + bv[nt];
                    hv[nt] = v; sum += v; sq += v * v;
                }
                #pragma unroll
                for (int m = 1; m <= 8; m <<= 1) {
                    sum += __shfl_xor(sum, m, 64);
                    sq  += __shfl_xor(sq, m, 64);
                }
                float mean = sum * (1.f / 128.f);
                float inv  = rsqrtf(sq * (1.f / 128.f) - mean * mean + 1e-5f);
                int row = lrow0 + reg;
                if (row < NN) {
                    #pragma unroll
                    for (int nt = 0; nt < 8; ++nt)
                        ident[row * 128 + nt * 16 + c] =
                            (hv[nt] - mean) * inv * gv[nt] + tv[nt];
                }
            }
        }
    }
}

// ---------------------------------------------------------------------------
// K3a: per-block degree sums.
// ---------------------------------------------------------------------------
__global__ __launch_bounds__(256) void k3a_blocksum(
    const int* __restrict__ deg, int* __restrict__ bsum)
{
    __shared__ int ws[4];
    int i = blockIdx.x * 256 + threadIdx.x;
    int v = (i < NN) ? deg[i] : 0;
    #pragma unroll
    for (int m = 32; m >= 1; m >>= 1) v += __shfl_xor(v, m, 64);
    if ((threadIdx.x & 63) == 0) ws[threadIdx.x >> 6] = v;
    __syncthreads();
    if (threadIdx.x == 0) bsum[blockIdx.x] = ws[0] + ws[1] + ws[2] + ws[3];
}

// ---------------------------------------------------------------------------
// K3c: each block reduces bsum[0..blockIdx) itself (<=195 values), then its
// local scan -> row_start + cursor. (k3b eliminated; total is static NE.)
// ---------------------------------------------------------------------------
__global__ __launch_bounds__(256) void k3c_apply(
    const int* __restrict__ deg, const int* __restrict__ bsum,
    int* __restrict__ row_start, int* __restrict__ cursor)
{
    __shared__ int wsum[4];
    __shared__ int roff[4];
    const int tid = threadIdx.x, lane = tid & 63, wid = tid >> 6;
    int bv = (tid < blockIdx.x) ? bsum[tid] : 0;   // blockIdx.x <= 195 < 256
    #pragma unroll
    for (int m = 32; m >= 1; m >>= 1) bv += __shfl_xor(bv, m, 64);
    if (lane == 0) roff[wid] = bv;

    int i = blockIdx.x * 256 + tid;
    int v = (i < NN) ? deg[i] : 0;
    int sc = v;
    #pragma unroll
    for (int m = 1; m < 64; m <<= 1) {
        int t = __shfl_up(sc, m, 64);
        if (lane >= m) sc += t;
    }
    if (lane == 63) wsum[wid] = sc;
    __syncthreads();
    int off = roff[0] + roff[1] + roff[2] + roff[3];
    for (int w = 0; w < wid; ++w) off += wsum[w];
    int excl = off + sc - v;
    if (i < NN) { row_start[i] = excl; cursor[i] = excl; }
}

// ---------------------------------------------------------------------------
// K4: scatter (edge id, src id) pairs into dst-sorted CSR order.
// ---------------------------------------------------------------------------
__global__ __launch_bounds__(256) void k4_scatter(
    const int* __restrict__ eidx, int* __restrict__ cursor,
    int2* __restrict__ csr_es)
{
    int e = blockIdx.x * 256 + threadIdx.x;
    if (e >= NE) return;
    int dst = eidx[NE + e];
    int srcn = eidx[e];
    int pos = atomicAdd(cursor + dst, 1);
    csr_es[pos] = make_int2(e, srcn);
}

// ---------------------------------------------------------------------------
// K5: fused GATv2 attention + aggregation. One wave per node.
// e-transform via v_dot2_f32_f16: ef pre-paired f16 (efp), W_e pre-paired
// per channel (Wep) -> 16 scalar unsigned resident (pinned with in-loop asm
// on SCALAR operands; vector-typed "+v" ties don't compile on gfx950).
// 16 dot2/edge instead of 32 fmac. 1-deep pipeline; 4-DPP logit reduce.
// ---------------------------------------------------------------------------
__global__ __launch_bounds__(256, 4) void k5_attn_aggregate(
    const int2* __restrict__ csr_es, const int* __restrict__ row_start,
    const unsigned* __restrict__ efp, const unsigned* __restrict__ Wep,
    const float* __restrict__ att,
    const float* __restrict__ x_l, const float* __restrict__ x_r,
    const float* __restrict__ gat_bias,
    float* __restrict__ gat_out)
{
    const int lane = threadIdx.x & 63;
    const int node = (blockIdx.x * 256 + threadIdx.x) >> 6;
    if (node >= NN) return;
    const int c = lane * 2;

    uint4 t0 = *(const uint4*)(Wep + c * 8);
    uint4 t1 = *(const uint4*)(Wep + c * 8 + 4);
    uint4 t2 = *(const uint4*)(Wep + (c + 1) * 8);
    uint4 t3 = *(const uint4*)(Wep + (c + 1) * 8 + 4);
    unsigned wx0 = t0.x, wx1 = t0.y, wx2 = t0.z, wx3 = t0.w;
    unsigned wx4 = t1.x, wx5 = t1.y, wx6 = t1.z, wx7 = t1.w;
    unsigned wy0 = t2.x, wy1 = t2.y, wy2 = t2.z, wy3 = t2.w;
    unsigned wy4 = t3.x, wy5 = t3.y, wy6 = t3.z, wy7 = t3.w;

    const float2 a2 = *(const float2*)(att + c);
    const float2 xr = *(const float2*)(x_r + node * 128 + c);
    const uint4* __restrict__ efq = (const uint4*)efp;
    const float2* __restrict__ xlc = (const float2*)(x_l + c);

    const int sj  = rfl(row_start[node]);
    const int epj = rfl(row_start[node + 1]);

    float den = 0.f, n0 = 0.f, n1 = 0.f;

    if (sj < epj) {
        int2 es0 = csr_es[sj];
        int eid = rfl(es0.x), src = rfl(es0.y);
        uint4 E0 = efq[eid * 2 + 0], E1 = efq[eid * 2 + 1];
        float2 X = xlc[src * 64];

        for (int j = sj; j < epj; ++j) {
            asm volatile("" : "+v"(wx0), "+v"(wx1), "+v"(wx2), "+v"(wx3),
                              "+v"(wx4), "+v"(wx5), "+v"(wx6), "+v"(wx7));
            asm volatile("" : "+v"(wy0), "+v"(wy1), "+v"(wy2), "+v"(wy3),
                              "+v"(wy4), "+v"(wy5), "+v"(wy6), "+v"(wy7));
            uint4 cE0 = E0, cE1 = E1;
            float2 cX = X;
            if (j + 1 < epj) {
                int2 es = csr_es[j + 1];
                int e1 = rfl(es.x), s1 = rfl(es.y);
                E0 = efq[e1 * 2 + 0]; E1 = efq[e1 * 2 + 1];
                X = xlc[s1 * 64];
            }
            float ax = cX.x + xr.x;
            float bx = 0.f;
            float ay = cX.y + xr.y;
            float by = 0.f;
            ax = fdot2u(cE0.x, wx0, ax);  ay = fdot2u(cE0.x, wy0, ay);
            bx = fdot2u(cE0.y, wx1, bx);  by = fdot2u(cE0.y, wy1, by);
            ax = fdot2u(cE0.z, wx2, ax);  ay = fdot2u(cE0.z, wy2, ay);
            bx = fdot2u(cE0.w, wx3, bx);  by = fdot2u(cE0.w, wy3, by);
            ax = fdot2u(cE1.x, wx4, ax);  ay = fdot2u(cE1.x, wy4, ay);
            bx = fdot2u(cE1.y, wx5, bx);  by = fdot2u(cE1.y, wy5, by);
            ax = fdot2u(cE1.z, wx6, ax);  ay = fdot2u(cE1.z, wy6, ay);
            bx = fdot2u(cE1.w, wx7, bx);  by = fdot2u(cE1.w, wy7, by);
            float evx = ax + bx;
            float evy = ay + by;

            float lx = fmaxf(evx, 0.2f * evx);
            float ly = fmaxf(evy, 0.2f * evy);
            float p = lx * a2.x + ly * a2.y;
            p = dpp_reduce16(p);
            float ev = __expf(p);
            den += ev;
            n0 += ev * cX.x;
            n1 += ev * cX.y;
        }
    }
    float rden = (den > 0.f) ? (1.f / den) : 0.f;
    float2 gb = *(const float2*)(gat_bias + c);
    float2 o; o.x = n0 * rden + gb.x; o.y = n1 * rden + gb.y;
    *(float2*)(gat_out + node * 128 + c) = o;
}

// ---------------------------------------------------------------------------
// K6 (MFMA): MLP + LN + residual add.  (unchanged)
// ---------------------------------------------------------------------------
__global__ __launch_bounds__(256, 4) void k6_mlp_mfma(
    const float* __restrict__ nf, const float* __restrict__ gat,
    const float* __restrict__ ident,
    const unsigned short* __restrict__ Wt0, const float* __restrict__ b0,
    const float* __restrict__ g0, const float* __restrict__ be0,
    const unsigned short* __restrict__ Wt1, const float* __restrict__ b1,
    const float* __restrict__ g1, const float* __restrict__ be1,
    float* __restrict__ out)
{
    __shared__ __align__(16) unsigned LDS[64 * 100];
    const int tid = threadIdx.x;
    const int node0 = blockIdx.x * 64;

    for (int i = tid; i < 64 * 96; i += 256) {
        int n = i / 96, c2 = i - n * 96;
        int gn = node0 + n;
        float2 v = make_float2(0.f, 0.f);
        if (gn < NN)
            v = (c2 < 32) ? *(const float2*)(nf + gn * 64 + 2 * c2)
                          : *(const float2*)(gat + gn * 128 + 2 * (c2 - 32));
        LDS[n * 100 + c2] = pkbf(v.x, v.y);
    }
    __syncthreads();

    const int lane = tid & 63, w = tid >> 6;
    const int c = lane & 15, ko = lane >> 4;
    const int lrow = w * 16 + 4 * ko;

    f32x4 acc[8];
    #pragma unroll
    for (int nt = 0; nt < 8; ++nt) acc[nt] = f32x4{0.f, 0.f, 0.f, 0.f};

    #pragma unroll
    for (int kb = 0; kb < 6; ++kb) {
        bf16x8 a = *(const bf16x8*)((const unsigned short*)LDS +
                                    (w * 16 + c) * 200 + kb * 32 + ko * 8);
        #pragma unroll
        for (int nt = 0; nt < 8; ++nt) {
            bf16x8 b = *(const bf16x8*)(Wt0 + (nt * 16 + c) * 192 + kb * 32 + ko * 8);
            acc[nt] = __builtin_amdgcn_mfma_f32_16x16x32_bf16(a, b, acc[nt], 0, 0, 0);
        }
    }

    float bv[8], gv[8], tv[8];
    #pragma unroll
    for (int nt = 0; nt < 8; ++nt) {
        bv[nt] = b0[nt * 16 + c];
        gv[nt] = g0[nt * 16 + c];
        tv[nt] = be0[nt * 16 + c];
    }
    __syncthreads();

    unsigned short* Hs = (unsigned short*)LDS;
    #pragma unroll
    for (int reg = 0; reg < 4; ++reg) {
        float sum = 0.f, sq = 0.f, hv[8];
        #pragma unroll
        for (int nt = 0; nt < 8; ++nt) {
            float v = acc[nt][reg] + bv[nt];
            hv[nt] = v; sum += v; sq += v * v;
        }
        #pragma unroll
        for (int m = 1; m <= 8; m <<= 1) {
            sum += __shfl_xor(sum, m, 64);
            sq  += __shfl_xor(sq, m, 64);
        }
        float mean = sum * (1.f / 128.f);
        float inv  = rsqrtf(sq * (1.f / 128.f) - mean * mean + 1e-5f);
        #pragma unroll
        for (int nt = 0; nt < 8; ++nt) {
            float h = fmaxf((hv[nt] - mean) * inv * gv[nt] + tv[nt], 0.f);
            Hs[(lrow + reg) * 136 + nt * 16 + c] = bfb(h);
        }
    }
    __syncthreads();

    #pragma unroll
    for (int nt = 0; nt < 8; ++nt) acc[nt] = f32x4{0.f, 0.f, 0.f, 0.f};
    #pragma unroll
    for (int kb = 0; kb < 4; ++kb) {
        bf16x8 a = *(const bf16x8*)((const unsigned short*)LDS +
                                    (w * 16 + c) * 136 + kb * 32 + ko * 8);
        #pragma unroll
        for (int nt = 0; nt < 8; ++nt) {
            bf16x8 b = *(const bf16x8*)(Wt1 + (nt * 16 + c) * 128 + kb * 32 + ko * 8);
            acc[nt] = __builtin_amdgcn_mfma_f32_16x16x32_bf16(a, b, acc[nt], 0, 0, 0);
        }
    }

    #pragma unroll
    for (int nt = 0; nt < 8; ++nt) {
        bv[nt] = b1[nt * 16 + c];
        gv[nt] = g1[nt * 16 + c];
        tv[nt] = be1[nt * 16 + c];
    }
    #pragma unroll
    for (int reg = 0; reg < 4; ++reg) {
        float sum = 0.f, sq = 0.f, hv[8];
        #pragma unroll
        for (int nt = 0; nt < 8; ++nt) {
            float v = acc[nt][reg] + bv[nt];
            hv[nt] = v; sum += v; sq += v * v;
        }
        #pragma unroll
        for (int m = 1; m <= 8; m <<= 1) {
            sum += __shfl_xor(sum, m, 64);
            sq  += __shfl_xor(sq, m, 64);
        }
        float mean = sum * (1.f / 128.f);
        float inv  = rsqrtf(sq * (1.f / 128.f) - mean * mean + 1e-5f);
        int row = node0 + lrow + reg;
        if (row < NN) {
            #pragma unroll
            for (int nt = 0; nt < 8; ++nt) {
                float h = fmaxf((hv[nt] - mean) * inv * gv[nt] + tv[nt], 0.f);
                int col = nt * 16 + c;
                out[row * 128 + col] = ident[row * 128 + col] + h;
            }
        }
    }
}

// ---------------------------------------------------------------------------
extern "C" void kernel_launch(void* const* d_in, const int* in_sizes, int n_in,
                              void* d_out, int out_size, void* d_ws, size_t ws_size,
                              hipStream_t stream)
{
    const float* nf       = (const float*)d_in[0];
    const float* ef       = (const float*)d_in[1];
    const int*   eidx     = (const int*)d_in[2];
    const float* W_l      = (const float*)d_in[3];
    const float* b_l      = (const float*)d_in[4];
    const float* W_r      = (const float*)d_in[5];
    const float* b_r      = (const float*)d_in[6];
    const float* W_e      = (const float*)d_in[7];
    const float* att      = (const float*)d_in[8];
    const float* gat_bias = (const float*)d_in[9];
    const float* res_W    = (const float*)d_in[10];
    const float* res_b    = (const float*)d_in[11];
    const float* res_g    = (const float*)d_in[12];
    const float* res_beta = (const float*)d_in[13];
    const float* W0       = (const float*)d_in[14];
    const float* b0       = (const float*)d_in[15];
    const float* g0       = (const float*)d_in[16];
    const float* beta0    = (const float*)d_in[17];
    const float* W1       = (const float*)d_in[18];
    const float* b1       = (const float*)d_in[19];
    const float* g1       = (const float*)d_in[20];
    const float* beta1    = (const float*)d_in[21];
    float* out = (float*)d_out;

    char* ws = (char*)d_ws;
    size_t off = 0;
    auto alloc = [&](size_t bytes) -> void* {
        void* p = ws + off;
        off += (bytes + 255) & ~(size_t)255;
        return p;
    };
    float* x_l     = (float*)alloc((size_t)NN * 128 * 4);
    float* x_r     = (float*)alloc((size_t)NN * 128 * 4);
    float* ident   = (float*)alloc((size_t)NN * 128 * 4);
    int* deg       = (int*)alloc((size_t)NN * 4);
    int* row_start = (int*)alloc((size_t)(NN + 1) * 4);
    int* cursor    = (int*)alloc((size_t)NN * 4);
    int* bsum      = (int*)alloc((size_t)(NB + 1) * 4);
    int2* csr_es   = (int2*)alloc((size_t)NE * 8);
    float* gat_out = (float*)alloc((size_t)NN * 128 * 4);
    unsigned short* Wtl   = (unsigned short*)alloc(8192 * 2);
    unsigned short* Wtr   = (unsigned short*)alloc(8192 * 2);
    unsigned short* Wtres = (unsigned short*)alloc(8192 * 2);
    unsigned short* Wt0   = (unsigned short*)alloc(24576 * 2);
    unsigned short* Wt1   = (unsigned short*)alloc(16384 * 2);
    unsigned* Wep = (unsigned*)alloc(1024 * 4);
    unsigned* efp = (unsigned*)alloc((size_t)NE * 8 * 4);

    k0_prep<<<8192, 256, 0, stream>>>(W_l, W_r, res_W, W0, W1, W_e, ef,
                                      Wtl, Wtr, Wtres, Wt0, Wt1, Wep, efp,
                                      deg, row_start);

    ka_nodes_degree<<<K1B + (NE + 255) / 256, 256, 0, stream>>>(
        nf, Wtl, b_l, Wtr, b_r, Wtres, res_b, res_g, res_beta,
        x_l, x_r, ident, eidx, deg);

    k3a_blocksum<<<NB, 256, 0, stream>>>(deg, bsum);
    k3c_apply<<<NB, 256, 0, stream>>>(deg, bsum, row_start, cursor);

    k4_scatter<<<(NE + 255) / 256, 256, 0, stream>>>(eidx, cursor, csr_es);

    k5_attn_aggregate<<<(NN * 64 + 255) / 256, 256, 0, stream>>>(
        csr_es, row_start, efp, Wep, att, x_l, x_r, gat_bias, gat_out);

    k6_mlp_mfma<<<(NN + 63) / 64, 256, 0, stream>>>(
        nf, gat_out, ident, Wt0, b0, g0, beta0, Wt1, b1, g1, beta1, out);
}